// Round 6
// baseline (878.506 us; speedup 1.0000x reference)
//
#include <hip/hip_runtime.h>

// ---------------------------------------------------------------------------
// ConvBERT layer forward, bf16 compute / fp32 accumulate.
// B=8 S=1024 H=1536 NH=8 HD=96 AH=768 K=7 IM=3072
// Round 13: dispatch-count + redundant-pass reduction.
//   - prep_weights: ONE launch = QKVco-wT + pwT + wckT + dwT + cbias
//   - prep_late:    ONE launch = wsoT + wiT + woT (after flash frees B)
//   - gemm256 epilogue learns a residual input (wso:+ebuf, wo:+attn, f32 add)
//     -> ln_kernel is single-input (saves 2x25MB reads)
//   - ck_softmax folded into conv_out (inline per-thread softmax)
//   25 -> 18 dispatches. gemm256 v3 compute loop frozen.
// ---------------------------------------------------------------------------

typedef __bf16 bf16_t;
typedef short s16x8 __attribute__((ext_vector_type(8)));   // 8 bf16 in 4 VGPRs
typedef float f32x4 __attribute__((ext_vector_type(4)));

#define BB  8
#define SS  1024
#define HH  1536
#define NHH 8
#define HDD 96
#define AHH 768
#define IMM 3072

__device__ __forceinline__ float rd_adapt(const void* p, long long i, int isbf) {
    return isbf ? (float)((const bf16_t*)p)[i] : ((const float*)p)[i];
}
// bf16 bits -> f32 (bf16 is upper 16 bits of f32)
__device__ __forceinline__ float bs2f(short x) {
    return __uint_as_float(((unsigned)(unsigned short)x) << 16);
}
// f32 -> bf16 bits (RNE via hardware cvt)
__device__ __forceinline__ short f2bs(float f) {
    bf16_t b = (bf16_t)f; short s; __builtin_memcpy(&s, &b, 2); return s;
}

// tanh-form GELU: max |diff| vs exact erf-GELU ~3e-3, far under bf16 budget
__device__ __forceinline__ float gelu_f(float v) {
    float u = v * (0.7978845608f + 0.0356774081f * v * v);
    float e = __expf(2.0f * u);
    float t = 1.0f - 2.0f / (e + 1.0f);
    return 0.5f * v * (1.0f + t);
}

// async global->LDS, 16B per lane; lds base must be wave-uniform
__device__ __forceinline__ void gl2lds16(const bf16_t* g, bf16_t* l) {
    __builtin_amdgcn_global_load_lds(
        (__attribute__((address_space(1))) const void*)g,
        (__attribute__((address_space(3))) void*)l, 16, 0, 0);
}

#define FENCE() asm volatile("" ::: "memory")
#define BARRIER() do { FENCE(); __builtin_amdgcn_s_barrier(); FENCE(); } while (0)
#define LGKM(n) asm volatile("s_waitcnt lgkmcnt(" #n ")" ::: "memory")
#define VMCNT(n) asm volatile("s_waitcnt vmcnt(" #n ")" ::: "memory")
#define SCHEDB() __builtin_amdgcn_sched_barrier(0)
#define PRIO(n) __builtin_amdgcn_s_setprio(n)
#define RDV(base, imm) (*(const s16x8*)(smb + (base) + (imm)))

#define MFMA_CLUSTER(AF, BF, IO, JO)                                            \
    _Pragma("unroll")                                                           \
    for (int i_ = 0; i_ < 4; i_++)                                              \
        _Pragma("unroll")                                                       \
        for (int j_ = 0; j_ < 2; j_++) {                                        \
            acc[(IO)+i_][(JO)+j_] = __builtin_amdgcn_mfma_f32_16x16x32_bf16(    \
                AF[i_][0], BF[j_][0], acc[(IO)+i_][(JO)+j_], 0, 0, 0);          \
            acc[(IO)+i_][(JO)+j_] = __builtin_amdgcn_mfma_f32_16x16x32_bf16(    \
                AF[i_][1], BF[j_][1], acc[(IO)+i_][(JO)+j_], 0, 0, 0);          \
        }

// ---------------------------------------------------------------------------
// dtype probe: bf16 vs fp32 inputs. flag=1 -> bf16.
// ---------------------------------------------------------------------------
__global__ __launch_bounds__(256)
void detect_kernel(const void* __restrict__ embed, int* __restrict__ flag)
{
    __shared__ int cnt[256];
    int t = threadIdx.x;
    float x = (float)((const bf16_t*)embed)[t];
    float a = fabsf(x);
    cnt[t] = (a > 1e-3f && a < 50.0f) ? 1 : 0;
    __syncthreads();
    for (int o = 128; o > 0; o >>= 1) { if (t < o) cnt[t] += cnt[t + o]; __syncthreads(); }
    if (t == 0) *flag = (cnt[0] >= 205) ? 1 : 0;
}

__global__ __launch_bounds__(256)
void convert_embed(const void* __restrict__ in, bf16_t* __restrict__ out,
                   const int* __restrict__ flagp)
{
    int isbf = *flagp;
    long long i0 = ((long long)blockIdx.x * 256 + threadIdx.x) * 8;
    if (isbf) {
        *(s16x8*)(out + i0) = *(const s16x8*)((const bf16_t*)in + i0);
    } else {
        const float* f = (const float*)in;
        #pragma unroll
        for (int j = 0; j < 8; j++) out[i0 + j] = (bf16_t)f[i0 + j];
    }
}

// ---------------------------------------------------------------------------
// Generic 64x64 transpose tile body (shared-mem staged, 16B in / 16B out).
// in[R' rows][C cols] (ldin), writes out[(cb+oc)*R + rb+r], zero-pad col>=C.
// ---------------------------------------------------------------------------
__device__ __forceinline__ void tr64_body(const void* in, bf16_t* out,
                                          int C, int ldin, int R,
                                          int cb, int rb, int isbf,
                                          bf16_t (*t)[72])
{
    int tr = threadIdx.x >> 3;           // 0..31
    int tc = (threadIdx.x & 7) * 8;      // 0..56
    #pragma unroll
    for (int it = 0; it < 2; it++) {
        int r = tr + it * 32;
        int gc = cb + tc;
        if (isbf && gc + 8 <= C) {
            *(s16x8*)&t[r][tc] =
                *(const s16x8*)((const bf16_t*)in + (long long)(rb + r) * ldin + gc);
        } else {
            #pragma unroll
            for (int j = 0; j < 8; j++)
                t[r][tc + j] = (gc + j < C)
                    ? (bf16_t)rd_adapt(in, (long long)(rb + r) * ldin + gc + j, isbf)
                    : (bf16_t)0.0f;
        }
    }
    __syncthreads();
    int oc = threadIdx.x >> 2;           // 0..63
    int r0 = (threadIdx.x & 3) * 16;
    s16x8 v0, v1;
    #pragma unroll
    for (int j = 0; j < 8; j++) v0[j] = *(short*)&t[r0 + j][oc];
    #pragma unroll
    for (int j = 0; j < 8; j++) v1[j] = *(short*)&t[r0 + 8 + j][oc];
    bf16_t* dst = out + (long long)(cb + oc) * R + rb + r0;
    *(s16x8*)dst = v0;
    *(s16x8*)(dst + 8) = v1;
}

// ---------------------------------------------------------------------------
// prep_weights: one launch for all early weight prep.
//  jobs [0,1152): wq|wk|wv|wco [1536,768] -> wT_all[z][768][1536]
//  jobs [1152,1440): pw -> pwT[768][1536]
//  jobs [1440,1464): wck [768,56] -> wckT[128][768] (zero-padded)
//  jobs [1464,1506): dwT f32 [7][1536]
//  jobs [1506,1518): cbias[3072]
// ---------------------------------------------------------------------------
__global__ __launch_bounds__(256)
void prep_weights(const void* __restrict__ wq, const void* __restrict__ wk,
                  const void* __restrict__ wv, const void* __restrict__ wco,
                  const void* __restrict__ pw, const void* __restrict__ wck,
                  const void* __restrict__ dw,
                  const void* __restrict__ b0, const void* __restrict__ b1,
                  const void* __restrict__ b2, const void* __restrict__ b3,
                  bf16_t* __restrict__ wT_all, bf16_t* __restrict__ pwT,
                  bf16_t* __restrict__ wckT, float* __restrict__ dwT,
                  bf16_t* __restrict__ cbias, const int* __restrict__ flagp)
{
    __shared__ bf16_t t[64][72];
    int isbf = *flagp;
    int j = blockIdx.x;
    if (j < 1152) {
        int z = j / 288, rm = j % 288;
        const void* in = (z == 0) ? wq : (z == 1) ? wk : (z == 2) ? wv : wco;
        tr64_body(in, wT_all + (long long)z * 768 * 1536, 768, 768, 1536,
                  (rm % 12) * 64, (rm / 12) * 64, isbf, t);
    } else if (j < 1440) {
        int rm = j - 1152;
        tr64_body(pw, pwT, 768, 768, 1536, (rm % 12) * 64, (rm / 12) * 64, isbf, t);
    } else if (j < 1464) {
        int rm = j - 1440;
        tr64_body(wck, wckT, 56, 56, 768, (rm % 2) * 64, (rm / 2) * 64, isbf, t);
    } else if (j < 1506) {
        int idx = (j - 1464) * 256 + threadIdx.x;     // < 10752 exactly
        int k = idx % 7, c = idx / 7;
        dwT[k * HH + c] = rd_adapt(dw, (long long)c * 7 + k, isbf);
    } else {
        int tt = (j - 1506) * 256 + threadIdx.x;      // < 3072
        int sel = tt / 768, off = tt - sel * 768;
        const void* src = (sel == 0) ? b0 : (sel == 1) ? b1 : (sel == 2) ? b2 : b3;
        cbias[tt] = (bf16_t)rd_adapt(src, off, isbf);
    }
}

// ---------------------------------------------------------------------------
// prep_late: wsoT + wiT + woT in one launch (runs after flash frees B slot).
//  jobs [0,576): wso [1536,1536] -> wsoT[1536][1536]
//  jobs [576,1728): wi [1536,3072] -> wiT[3072][1536]
//  jobs [1728,2880): wo [3072,1536] -> woT[1536][3072]
// ---------------------------------------------------------------------------
__global__ __launch_bounds__(256)
void prep_late(const void* __restrict__ wso, const void* __restrict__ wi,
               const void* __restrict__ wo, bf16_t* __restrict__ wsoT,
               bf16_t* __restrict__ wiT, bf16_t* __restrict__ woT,
               const int* __restrict__ flagp)
{
    __shared__ bf16_t t[64][72];
    int isbf = *flagp;
    int j = blockIdx.x;
    if (j < 576) {
        tr64_body(wso, wsoT, 1536, 1536, 1536, (j % 24) * 64, (j / 24) * 64, isbf, t);
    } else if (j < 1728) {
        int rm = j - 576;
        tr64_body(wi, wiT, 3072, 3072, 1536, (rm % 48) * 64, (rm / 48) * 64, isbf, t);
    } else {
        int rm = j - 1728;
        tr64_body(wo, woT, 1536, 1536, 3072, (rm % 24) * 64, (rm / 24) * 64, isbf, t);
    }
}

// ---------------------------------------------------------------------------
// gemm256 v3 (frozen loop): 256x256 tile, BK=64, 512 thr = 8 waves (2M x 4N).
// Epilogue: D = post(acc + bias [+resi] [*emul] [gelu]).
// ---------------------------------------------------------------------------
template<int IB, int OB>
__device__ __forceinline__ void tile_step(
    char* smb, int vA0, int vA1, int vB0, int vB1,
    const char* gA00, const char* gA01, const char* gA10, const char* gA11,
    const char* gB00, const char* gB01, const char* gB10, const char* gB11,
    char* ldsAw, char* ldsBw, int k1, int k2,
    s16x8 (&af0)[4][2], s16x8 (&af1)[4][2],
    s16x8 (&bf0)[2][2], s16x8 (&bf1)[2][2],
    f32x4 (&acc)[8][4])
{
    // ---- phase 1: MFMA af0 x bf0; issue bf1 reads; stage A-h1(t+1)->OB ----
    BARRIER();
    bf1[0][0] = RDV(vB0, IB + 4096); bf1[0][1] = RDV(vB1, IB + 4096);
    bf1[1][0] = RDV(vB0, IB + 6144); bf1[1][1] = RDV(vB1, IB + 6144);
    gl2lds16((const bf16_t*)(gA10 + k1), (bf16_t*)(ldsAw + OB + 16384));
    gl2lds16((const bf16_t*)(gA11 + k1), (bf16_t*)(ldsAw + OB + 17408));
    LGKM(4); SCHEDB(); PRIO(1);
    MFMA_CLUSTER(af0, bf0, 0, 0);
    PRIO(0);

    // ---- phase 2: MFMA af0 x bf1; issue af1 reads; stage B-h1(t+1)->OB ----
    BARRIER();
    af1[0][0] = RDV(vA0, IB + 8192);  af1[0][1] = RDV(vA1, IB + 8192);
    af1[1][0] = RDV(vA0, IB + 10240); af1[1][1] = RDV(vA1, IB + 10240);
    af1[2][0] = RDV(vA0, IB + 12288); af1[2][1] = RDV(vA1, IB + 12288);
    af1[3][0] = RDV(vA0, IB + 14336); af1[3][1] = RDV(vA1, IB + 14336);
    gl2lds16((const bf16_t*)(gB10 + k1), (bf16_t*)(ldsBw + OB + 16384));
    gl2lds16((const bf16_t*)(gB11 + k1), (bf16_t*)(ldsBw + OB + 17408));
    LGKM(8); SCHEDB(); PRIO(1);
    MFMA_CLUSTER(af0, bf1, 0, 2);
    PRIO(0);

    // ---- phase 3: MFMA af1 x bf1; stage B-h0 + A-h0 (t+2)->IB ----
    BARRIER();
    gl2lds16((const bf16_t*)(gB00 + k2), (bf16_t*)(ldsBw + IB));
    gl2lds16((const bf16_t*)(gB01 + k2), (bf16_t*)(ldsBw + IB + 1024));
    gl2lds16((const bf16_t*)(gA00 + k2), (bf16_t*)(ldsAw + IB));
    gl2lds16((const bf16_t*)(gA01 + k2), (bf16_t*)(ldsAw + IB + 1024));
    LGKM(0); SCHEDB(); PRIO(1);
    MFMA_CLUSTER(af1, bf1, 4, 2);
    PRIO(0);

    // ---- phase 4: t+1 landed; MFMA af1 x bf0; preload af0'/bf0' from OB ----
    VMCNT(4);
    BARRIER();
    af0[0][0] = RDV(vA0, OB + 0);    af0[0][1] = RDV(vA1, OB + 0);
    af0[1][0] = RDV(vA0, OB + 2048); af0[1][1] = RDV(vA1, OB + 2048);
    af0[2][0] = RDV(vA0, OB + 4096); af0[2][1] = RDV(vA1, OB + 4096);
    af0[3][0] = RDV(vA0, OB + 6144); af0[3][1] = RDV(vA1, OB + 6144);
    PRIO(1);
    MFMA_CLUSTER(af1, bf0, 4, 0);
    PRIO(0);
    bf0[0][0] = RDV(vB0, OB + 0);    bf0[0][1] = RDV(vB1, OB + 0);
    bf0[1][0] = RDV(vB0, OB + 2048); bf0[1][1] = RDV(vB1, OB + 2048);
}

__global__ __launch_bounds__(512, 2)
void gemm256(const bf16_t* __restrict__ A, const bf16_t* __restrict__ Bt,
             bf16_t* __restrict__ C, const void* __restrict__ bias,
             const bf16_t* __restrict__ resi, int ldr,
             const bf16_t* __restrict__ emul, int lde, const int* __restrict__ flagp,
             int M, int N, int Kd, int lda, int ldb, int ldc, int act, int tilesN)
{
    __shared__ bf16_t Sm[65536];   // 128 KiB
    char* smb = (char*)Sm;
    int isbf = flagp ? *flagp : 1;

    // bijective XCD remap (m204) of the linear tile id; n fastest inside
    int nwg = gridDim.x;
    int orig = blockIdx.x;
    int q = nwg >> 3, r = nwg & 7;
    int xcd = orig & 7, lid = orig >> 3;
    int wg = (xcd < r ? xcd * (q + 1) : r * (q + 1) + (xcd - r) * q) + lid;
    int row0 = (wg / tilesN) * 256;
    int col0 = (wg % tilesN) * 256;

    int tid = threadIdx.x;
    int wave = tid >> 6, lane = tid & 63;
    int wm = wave >> 2, wn = wave & 3;
    int lm = lane & 15, kq = lane >> 4;

    // ---- staging geometry: wave w loads chunks {2w,2w+1} of each 16KB half
    int srow = lane >> 3;                       // 0..7 row within 1KB chunk
    int scol = 8 * ((lane & 7) ^ srow);         // pre-swizzled source col (bf16)

    // per-lane global byte bases [h][l]
    const char* gA00 = (const char*)(A + (long long)(row0 +   0 + (2*wave + 0)*8 + srow) * lda + scol);
    const char* gA01 = (const char*)(A + (long long)(row0 +   0 + (2*wave + 1)*8 + srow) * lda + scol);
    const char* gA10 = (const char*)(A + (long long)(row0 + 128 + (2*wave + 0)*8 + srow) * lda + scol);
    const char* gA11 = (const char*)(A + (long long)(row0 + 128 + (2*wave + 1)*8 + srow) * lda + scol);
    const char* gB00 = (const char*)(Bt + (long long)(col0 +   0 + (2*wave + 0)*8 + srow) * ldb + scol);
    const char* gB01 = (const char*)(Bt + (long long)(col0 +   0 + (2*wave + 1)*8 + srow) * ldb + scol);
    const char* gB10 = (const char*)(Bt + (long long)(col0 + 128 + (2*wave + 0)*8 + srow) * ldb + scol);
    const char* gB11 = (const char*)(Bt + (long long)(col0 + 128 + (2*wave + 1)*8 + srow) * ldb + scol);

    // wave-uniform LDS staging bases
    char* ldsAw = smb + 2 * wave * 1024;            // A region
    char* ldsBw = smb + 65536 + 2 * wave * 1024;    // B region

    // ---- fragment-read base vaddrs (swizzled); all reads = vaddr + imm ----
    int xo = (lm & 7) << 4;
    int c0 = (kq * 16) ^ xo;
    int c1 = (64 + kq * 16) ^ xo;
    int vA0 = (wm * 128 + lm) * 128 + c0;
    int vA1 = (wm * 128 + lm) * 128 + c1;
    int vB0 = 65536 + (wn * 64 + lm) * 128 + c0;
    int vB1 = 65536 + (wn * 64 + lm) * 128 + c1;

    f32x4 acc[8][4] = {};
    s16x8 af0[4][2], af1[4][2], bf0[2][2], bf1[2][2];

    int KT = Kd >> 6;
    int KTm1 = KT - 1;

    // ---- prologue: tile0 all 4 halves + tile1 B-h0/A-h0 ----
    gl2lds16((const bf16_t*)gA00, (bf16_t*)(ldsAw));
    gl2lds16((const bf16_t*)gA01, (bf16_t*)(ldsAw + 1024));
    gl2lds16((const bf16_t*)gA10, (bf16_t*)(ldsAw + 16384));
    gl2lds16((const bf16_t*)gA11, (bf16_t*)(ldsAw + 17408));
    gl2lds16((const bf16_t*)gB00, (bf16_t*)(ldsBw));
    gl2lds16((const bf16_t*)gB01, (bf16_t*)(ldsBw + 1024));
    gl2lds16((const bf16_t*)gB10, (bf16_t*)(ldsBw + 16384));
    gl2lds16((const bf16_t*)gB11, (bf16_t*)(ldsBw + 17408));
    int kb1 = min(1, KTm1) << 7;
    gl2lds16((const bf16_t*)(gB00 + kb1), (bf16_t*)(ldsBw + 32768));
    gl2lds16((const bf16_t*)(gB01 + kb1), (bf16_t*)(ldsBw + 33792));
    gl2lds16((const bf16_t*)(gA00 + kb1), (bf16_t*)(ldsAw + 32768));
    gl2lds16((const bf16_t*)(gA01 + kb1), (bf16_t*)(ldsAw + 33792));
    VMCNT(4);
    BARRIER();
    // R1(0): af0 + bf0 from buf0
    af0[0][0] = RDV(vA0, 0);    af0[0][1] = RDV(vA1, 0);
    af0[1][0] = RDV(vA0, 2048); af0[1][1] = RDV(vA1, 2048);
    af0[2][0] = RDV(vA0, 4096); af0[2][1] = RDV(vA1, 4096);
    af0[3][0] = RDV(vA0, 6144); af0[3][1] = RDV(vA1, 6144);
    bf0[0][0] = RDV(vB0, 0);    bf0[0][1] = RDV(vB1, 0);
    bf0[1][0] = RDV(vB0, 2048); bf0[1][1] = RDV(vB1, 2048);

    for (int it = 0; it < (KT >> 1); ++it) {
        int t = it << 1;
        int k1 = min(t + 1, KTm1) << 7;
        int k2 = min(t + 2, KTm1) << 7;
        int k3 = min(t + 3, KTm1) << 7;
        tile_step<0, 32768>(smb, vA0, vA1, vB0, vB1,
                            gA00, gA01, gA10, gA11, gB00, gB01, gB10, gB11,
                            ldsAw, ldsBw, k1, k2, af0, af1, bf0, bf1, acc);
        tile_step<32768, 0>(smb, vA0, vA1, vB0, vB1,
                            gA00, gA01, gA10, gA11, gB00, gB01, gB10, gB11,
                            ldsAw, ldsBw, k2, k3, af0, af1, bf0, bf1, acc);
    }

    // ---- epilogue: D row = kq*4 + r, col = lm (m89/m91-verified) ----
    #pragma unroll
    for (int j = 0; j < 4; j++) {
        int gcol = col0 + wn * 64 + j * 16 + lm;
        float bv = bias ? rd_adapt(bias, gcol, isbf) : 0.0f;
        #pragma unroll
        for (int ip = 0; ip < 8; ip++) {
            int grow0 = row0 + wm * 128 + ip * 16 + kq * 4;
            #pragma unroll
            for (int r = 0; r < 4; r++) {
                float v = acc[ip][j][r] + bv;
                if (resi) v += (float)resi[(long long)(grow0 + r) * ldr + gcol];
                if (emul) v *= (float)emul[(long long)(grow0 + r) * lde + gcol];
                if (act) v = gelu_f(v);
                C[(long long)(grow0 + r) * ldc + gcol] = (bf16_t)v;
            }
        }
    }
}

// ---------------------------------------------------------------------------
// Legacy 128x128 GEMM (sep + tiny ck GEMM).
// ---------------------------------------------------------------------------
__global__ __launch_bounds__(256)
void gemm_tile(const bf16_t* __restrict__ A, const bf16_t* __restrict__ Bt,
               bf16_t* __restrict__ C, const void* __restrict__ bias, long long biasOff,
               const bf16_t* __restrict__ emul, int lde, const int* __restrict__ flagp,
               int M, int N, int Kd, int lda, int ldb, int ldc,
               float scale, int act, int beta, int nlim)
{
    __shared__ bf16_t Sm[16384];   // As: [2][128][32] at 0; Bs: [2][128][32] at 8192

    int isbf = flagp ? *flagp : 1;
    int tid  = threadIdx.x;
    int wave = tid >> 6, lane = tid & 63;
    int wm = wave >> 1, wn = wave & 1;
    int row0 = blockIdx.x * 128;
    int col0 = blockIdx.y * 128;
    int lm = lane & 15;
    int kq = lane >> 4;

    int sr = tid >> 2;            // 0..63
    int sc = (tid & 3) * 8;       // 0,8,16,24
    const bf16_t* ga0 = A + (long long)(row0 + sr) * lda + sc;
    const bf16_t* ga1 = A + (long long)(row0 + 64 + sr) * lda + sc;
    int br0 = min(col0 + sr, nlim);
    int br1 = min(col0 + 64 + sr, nlim);
    const bf16_t* gb0 = Bt + (long long)br0 * ldb + sc;
    const bf16_t* gb1 = Bt + (long long)br1 * ldb + sc;
    bf16_t* lw = Sm + wave * 512;   // wave-uniform staging base

    f32x4 acc[4][4] = {};

    for (int k0 = 0; k0 < Kd; k0 += 64) {
        #pragma unroll
        for (int h = 0; h < 2; h++) {
            int kh = k0 + h * 32;
            gl2lds16(ga0 + kh, lw + h * 4096);
            gl2lds16(ga1 + kh, lw + h * 4096 + 2048);
            gl2lds16(gb0 + kh, lw + 8192 + h * 4096);
            gl2lds16(gb1 + kh, lw + 8192 + h * 4096 + 2048);
        }
        __syncthreads();

        s16x8 af[2][4], bfr[2][4];
        #pragma unroll
        for (int h = 0; h < 2; h++) {
            #pragma unroll
            for (int i = 0; i < 4; i++)
                af[h][i] = *(const s16x8*)(Sm + h * 4096 + (wm * 64 + i * 16 + lm) * 32 + kq * 8);
            #pragma unroll
            for (int j = 0; j < 4; j++)
                bfr[h][j] = *(const s16x8*)(Sm + 8192 + h * 4096 + (wn * 64 + j * 16 + lm) * 32 + kq * 8);
        }
        #pragma unroll
        for (int i = 0; i < 4; i++)
            #pragma unroll
            for (int j = 0; j < 4; j++) {
                acc[i][j] = __builtin_amdgcn_mfma_f32_16x16x32_bf16(af[0][i], bfr[0][j], acc[i][j], 0, 0, 0);
                acc[i][j] = __builtin_amdgcn_mfma_f32_16x16x32_bf16(af[1][i], bfr[1][j], acc[i][j], 0, 0, 0);
            }
        __syncthreads();
    }

    // epilogue: D row = kq*4 + r, col = lm (m89/m91-verified)
    #pragma unroll
    for (int j = 0; j < 4; j++) {
        int gcol = col0 + wn * 64 + j * 16 + lm;
        if (gcol >= N) continue;
        float bv = bias ? rd_adapt(bias, biasOff + gcol, isbf) : 0.0f;
        #pragma unroll
        for (int i = 0; i < 4; i++) {
            int grow0 = row0 + wm * 64 + i * 16 + kq * 4;
            #pragma unroll
            for (int r = 0; r < 4; r++) {
                float v = acc[i][j][r] * scale + bv;
                long long ci = (long long)(grow0 + r) * ldc + gcol;
                if (beta) v += (float)C[ci];
                if (emul) v *= (float)emul[(long long)(grow0 + r) * lde + gcol];
                if (act) v = gelu_f(v);
                C[ci] = (bf16_t)v;
            }
        }
    }
}

// ---------------------------------------------------------------------------
// Fused flash attention. grid = (64 bh, 8 q-tiles), block = 256.
// K-tile staged once per block into swizzled LDS [3][128][32].
// ---------------------------------------------------------------------------
__global__ __launch_bounds__(256, 2)
void flash_attn(const bf16_t* __restrict__ qkv, const bf16_t* __restrict__ vT,
                bf16_t* __restrict__ ctxcat)
{
    const float ascale = 0.1020620726159658f;   // 1/sqrt(96)
    __shared__ bf16_t KL[12288];                // K tile [3][128][32] swizzled, 24KB
    __shared__ bf16_t Pl[4 * 32 * 136];         // per-wave P[32][136] (pad 8)

    int bh = blockIdx.x;
    int b = bh >> 3, h = bh & 7;
    const bf16_t* Qp = qkv  + (long long)b * SS * 3072 + h * HDD;
    const bf16_t* Kp = qkv  + (long long)b * SS * 3072 + 768 + h * HDD;
    const bf16_t* Vt = vT   + (long long)b * AHH * SS + (long long)h * HDD * SS;
    bf16_t*       Op = ctxcat + (long long)b * SS * HH + h * HDD;

    int tid = threadIdx.x, wave = tid >> 6, lane = tid & 63;
    int lm = lane & 15, kq = lane >> 4;
    int q0 = blockIdx.y * 128 + wave * 32;
    bf16_t* Pw = Pl + wave * 32 * 136;

    // ---- K staging: 24 chunks of 1KB (chunk = 16 rows of [32-feat] block).
    int srow_l = lane >> 2;                                   // 0..15
    int sslot  = ((lane & 3) ^ ((lane >> 3) & 3)) * 8;        // logical col (elem)
    auto stageK = [&](int kt) {
        #pragma unroll
        for (int i = 0; i < 6; i++) {
            int qc = wave + 4 * i;                            // 0..23
            int fb = qc >> 3, cc = qc & 7;
            gl2lds16(Kp + (long long)(kt * 128 + cc * 16 + srow_l) * 3072 + fb * 32 + sslot,
                     KL + qc * 512);
        }
    };
    const char* klb = (const char*)KL + lm * 64 + ((kq ^ ((lm >> 1) & 3)) << 4);

    s16x8 aq[2][3];
    #pragma unroll
    for (int i = 0; i < 2; i++)
        #pragma unroll
        for (int kf = 0; kf < 3; kf++)
            aq[i][kf] = *(const s16x8*)(Qp + (long long)(q0 + i * 16 + lm) * 3072 + kf * 32 + kq * 8);

    stageK(0);
    __syncthreads();

    f32x4 Oacc[2][6] = {};
    float mrow[2][4], lrow[2][4];
    #pragma unroll
    for (int i = 0; i < 2; i++)
        #pragma unroll
        for (int r = 0; r < 4; r++) { mrow[i][r] = -1e30f; lrow[i][r] = 0.0f; }

    for (int kt = 0; kt < 8; kt++) {
        f32x4 S[2][8] = {};
        #pragma unroll
        for (int j = 0; j < 8; j++) {
            s16x8 bk[3];
            #pragma unroll
            for (int kf = 0; kf < 3; kf++)
                bk[kf] = *(const s16x8*)(klb + kf * 8192 + j * 1024);
            #pragma unroll
            for (int i = 0; i < 2; i++)
                #pragma unroll
                for (int kf = 0; kf < 3; kf++)
                    S[i][j] = __builtin_amdgcn_mfma_f32_16x16x32_bf16(aq[i][kf], bk[kf], S[i][j], 0, 0, 0);
        }
        __syncthreads();                     // all waves done reading KL
        if (kt < 7) stageK(kt + 1);          // overwrite KL; lands under softmax+PV

        float mnew[2][4];
        #pragma unroll
        for (int i = 0; i < 2; i++) {
            #pragma unroll
            for (int r = 0; r < 4; r++) {
                float mx = -1e30f;
                #pragma unroll
                for (int j = 0; j < 8; j++) mx = fmaxf(mx, S[i][j][r]);
                #pragma unroll
                for (int msk = 1; msk <= 8; msk <<= 1) mx = fmaxf(mx, __shfl_xor(mx, msk));
                mnew[i][r] = fmaxf(mrow[i][r], mx * ascale);
            }
        }
        #pragma unroll
        for (int i = 0; i < 2; i++) {
            #pragma unroll
            for (int r = 0; r < 4; r++) {
                float al = __expf(mrow[i][r] - mnew[i][r]);
                lrow[i][r] *= al;
                #pragma unroll
                for (int n = 0; n < 6; n++) Oacc[i][n][r] *= al;
                mrow[i][r] = mnew[i][r];
            }
        }
        float psum[2][4] = {};
        #pragma unroll
        for (int i = 0; i < 2; i++) {
            #pragma unroll
            for (int j = 0; j < 8; j++) {
                #pragma unroll
                for (int r = 0; r < 4; r++) {
                    float p = __expf(S[i][j][r] * ascale - mnew[i][r]);
                    psum[i][r] += p;
                    Pw[(i * 16 + kq * 4 + r) * 136 + j * 16 + lm] = (bf16_t)p;
                }
            }
        }
        #pragma unroll
        for (int i = 0; i < 2; i++) {
            #pragma unroll
            for (int r = 0; r < 4; r++) {
                float t = psum[i][r];
                #pragma unroll
                for (int msk = 1; msk <= 8; msk <<= 1) t += __shfl_xor(t, msk);
                lrow[i][r] += t;
            }
        }

        s16x8 ap[2][4];
        #pragma unroll
        for (int i = 0; i < 2; i++)
            #pragma unroll
            for (int kf = 0; kf < 4; kf++)
                ap[i][kf] = *(const s16x8*)(Pw + (i * 16 + lm) * 136 + kf * 32 + kq * 8);
        #pragma unroll
        for (int n = 0; n < 6; n++) {
            s16x8 bv[4];
            #pragma unroll
            for (int kf = 0; kf < 4; kf++)
                bv[kf] = *(const s16x8*)(Vt + (long long)(n * 16 + lm) * SS + kt * 128 + kf * 32 + kq * 8);
            #pragma unroll
            for (int i = 0; i < 2; i++)
                #pragma unroll
                for (int kf = 0; kf < 4; kf++)
                    Oacc[i][n] = __builtin_amdgcn_mfma_f32_16x16x32_bf16(ap[i][kf], bv[kf], Oacc[i][n], 0, 0, 0);
        }
        __syncthreads();
    }

    #pragma unroll
    for (int i = 0; i < 2; i++) {
        #pragma unroll
        for (int n = 0; n < 6; n++) {
            #pragma unroll
            for (int r = 0; r < 4; r++) {
                int row = q0 + i * 16 + kq * 4 + r;
                int col = n * 16 + lm;
                Op[(long long)row * HH + col] = (bf16_t)(Oacc[i][n][r] / lrow[i][r]);
            }
        }
    }
}

// ---------------------------------------------------------------------------
// Vectorized tiled transpose (used for vT only).
// ---------------------------------------------------------------------------
__global__ __launch_bounds__(256)
void transpose_v8(const void* __restrict__ in, bf16_t* __restrict__ out,
                  int R, int C, int ldin, long long inOff,
                  long long sInB, long long sOutB, const int* __restrict__ flagp)
{
    __shared__ bf16_t t[64][72];
    int isbf = flagp ? *flagp : 1;
    int z = blockIdx.z;
    long long base = inOff + (long long)z * sInB;
    bf16_t* op = out + (long long)z * sOutB;
    int cb = blockIdx.x * 64, rb = blockIdx.y * 64;
    int tr = threadIdx.x >> 3;
    int tc = (threadIdx.x & 7) * 8;
    #pragma unroll
    for (int it = 0; it < 2; it++) {
        int r = tr + it * 32;
        int gc = cb + tc;
        if (isbf && gc + 8 <= C) {
            *(s16x8*)&t[r][tc] =
                *(const s16x8*)((const bf16_t*)in + base + (long long)(rb + r) * ldin + gc);
        } else {
            #pragma unroll
            for (int j = 0; j < 8; j++)
                t[r][tc + j] = (gc + j < C)
                    ? (bf16_t)rd_adapt(in, base + (long long)(rb + r) * ldin + gc + j, isbf)
                    : (bf16_t)0.0f;
        }
    }
    __syncthreads();
    int oc = threadIdx.x >> 2;
    int r0 = (threadIdx.x & 3) * 16;
    s16x8 v0, v1;
    #pragma unroll
    for (int j = 0; j < 8; j++) v0[j] = *(short*)&t[r0 + j][oc];
    #pragma unroll
    for (int j = 0; j < 8; j++) v1[j] = *(short*)&t[r0 + 8 + j][oc];
    bf16_t* dst = op + (long long)(cb + oc) * R + rb + r0;
    *(s16x8*)dst = v0;
    *(s16x8*)(dst + 8) = v1;
}

// depthwise conv k=7, 'same' padding along S — vectorized 8-wide channels
__global__ __launch_bounds__(256)
void dconv_kernel(const bf16_t* __restrict__ ebuf, const float* __restrict__ dwT,
                  bf16_t* __restrict__ out)
{
    long long i = (long long)blockIdx.x * 256 + threadIdx.x;   // < B*S*192
    int c8 = (int)(i % 192) * 8;
    long long bs = i / 192;
    int s = (int)(bs % SS);
    float acc[8] = {};
    #pragma unroll
    for (int k = 0; k < 7; k++) {
        int ss = s + k - 3;
        if (ss < 0 || ss >= SS) continue;
        s16x8 v = *(const s16x8*)(ebuf + (bs + (k - 3)) * HH + c8);
        const float4* wp = (const float4*)(dwT + k * HH + c8);
        float4 w0 = wp[0], w1 = wp[1];
        acc[0] += bs2f(v[0]) * w0.x; acc[1] += bs2f(v[1]) * w0.y;
        acc[2] += bs2f(v[2]) * w0.z; acc[3] += bs2f(v[3]) * w0.w;
        acc[4] += bs2f(v[4]) * w1.x; acc[5] += bs2f(v[5]) * w1.y;
        acc[6] += bs2f(v[6]) * w1.z; acc[7] += bs2f(v[7]) * w1.w;
    }
    s16x8 o;
    #pragma unroll
    for (int j = 0; j < 8; j++) o[j] = f2bs(acc[j]);
    *(s16x8*)(out + bs * HH + c8) = o;
}

// conv_out with inline ck-softmax: reads raw ck scores [8192,64] (h*7+k),
// computes softmax per-thread (12x redundant per (bs,h), VALU-cheap),
// writes right half of ctxcat. Vectorized 8-wide hd.
__global__ __launch_bounds__(256)
void conv_out_kernel(const bf16_t* __restrict__ co, int ldco,
                     const bf16_t* __restrict__ ckb, bf16_t* __restrict__ ctxcat)
{
    long long i = (long long)blockIdx.x * 256 + threadIdx.x;   // < B*S*96
    int ch = (int)(i % 96);
    long long bs = i / 96;
    int s = (int)(bs % SS);
    int hd0 = ch * 8;
    int h = hd0 / HDD;
    // inline softmax over k=7
    const bf16_t* src = ckb + bs * 64 + h * 7;
    float wk[7], mx = -1e30f;
    #pragma unroll
    for (int k = 0; k < 7; k++) { wk[k] = (float)src[k]; mx = fmaxf(mx, wk[k]); }
    float sum = 0.0f;
    #pragma unroll
    for (int k = 0; k < 7; k++) { wk[k] = expf(wk[k] - mx); sum += wk[k]; }
    float inv = 1.0f / sum;
    #pragma unroll
    for (int k = 0; k < 7; k++) wk[k] *= inv;

    float acc[8] = {};
    #pragma unroll
    for (int k = 0; k < 7; k++) {
        int ss = s + k - 3;
        if (ss < 0 || ss >= SS) continue;
        s16x8 v = *(const s16x8*)(co + (bs + (k - 3)) * ldco + hd0);
        #pragma unroll
        for (int j = 0; j < 8; j++) acc[j] += bs2f(v[j]) * wk[k];
    }
    s16x8 o;
    #pragma unroll
    for (int j = 0; j < 8; j++) o[j] = f2bs(acc[j]);
    *(s16x8*)(ctxcat + bs * HH + AHH + hd0) = o;
}

// LayerNorm over 1536 (single input; residual pre-added in gemm epilogue)
__global__ __launch_bounds__(192)
void ln_kernel(const bf16_t* __restrict__ y,
               const void* __restrict__ g, const void* __restrict__ bta,
               bf16_t* __restrict__ outb, const int* __restrict__ flagp)
{
    int isbf = *flagp;
    long long row = blockIdx.x;
    int tid = threadIdx.x;
    int c0 = tid * 8;
    s16x8 vy = *(const s16x8*)(y + row * HH + c0);
    float x[8], s = 0.0f, s2 = 0.0f;
    #pragma unroll
    for (int j = 0; j < 8; j++) {
        float v = bs2f(vy[j]);
        x[j] = v; s += v; s2 += v * v;
    }
    #pragma unroll
    for (int o = 32; o > 0; o >>= 1) { s += __shfl_down(s, o); s2 += __shfl_down(s2, o); }
    __shared__ float w1[3], w2[3];
    int lane = tid & 63, wv = tid >> 6;
    if (lane == 0) { w1[wv] = s; w2[wv] = s2; }
    __syncthreads();
    float S1 = w1[0] + w1[1] + w1[2];
    float S2 = w2[0] + w2[1] + w2[2];
    float mean = S1 * (1.0f / HH);
    float var  = S2 * (1.0f / HH) - mean * mean;
    float inv  = rsqrtf(var + 1e-12f);
    s16x8 o;
    #pragma unroll
    for (int j = 0; j < 8; j++) {
        float v = (x[j] - mean) * inv * rd_adapt(g, c0 + j, isbf) + rd_adapt(bta, c0 + j, isbf);
        o[j] = f2bs(v);
    }
    *(s16x8*)(outb + row * HH + c0) = o;
}

// maxpool phase 1: per-32-row partial max — 192 threads x 8 cols, vectorized
__global__ __launch_bounds__(192)
void maxpool_p1(const bf16_t* __restrict__ lo, float* __restrict__ part)
{
    int sc = blockIdx.x, b = blockIdx.y;       // 32 chunks x 8 batches
    int tid = threadIdx.x;
    int c0 = tid * 8;
    const bf16_t* p = lo + ((long long)b * SS + sc * 32) * HH + c0;
    float m[8];
    #pragma unroll
    for (int j = 0; j < 8; j++) m[j] = -1e30f;
    for (int r = 0; r < 32; r++) {
        s16x8 v = *(const s16x8*)(p + (long long)r * HH);
        #pragma unroll
        for (int j = 0; j < 8; j++) m[j] = fmaxf(m[j], bs2f(v[j]));
    }
    float* dst = part + ((long long)b * 32 + sc) * HH + c0;
    *(float4*)(dst)     = make_float4(m[0], m[1], m[2], m[3]);
    *(float4*)(dst + 4) = make_float4(m[4], m[5], m[6], m[7]);
}

// fused maxpool phase 2 + decoder — 192 threads x 8 cols
__global__ __launch_bounds__(192)
void pool_decode(const float* __restrict__ part, const void* __restrict__ wd,
                 const void* __restrict__ bd, void* __restrict__ out,
                 const int* __restrict__ flagp)
{
    int isbf = *flagp;
    int b = blockIdx.x;
    int tid = threadIdx.x;
    int c0 = tid * 8;
    float m[8];
    #pragma unroll
    for (int j = 0; j < 8; j++) m[j] = -1e30f;
    for (int ch = 0; ch < 32; ch++) {
        const float4* q = (const float4*)(part + ((long long)b * 32 + ch) * HH + c0);
        float4 a = q[0], c = q[1];
        m[0] = fmaxf(m[0], a.x); m[1] = fmaxf(m[1], a.y);
        m[2] = fmaxf(m[2], a.z); m[3] = fmaxf(m[3], a.w);
        m[4] = fmaxf(m[4], c.x); m[5] = fmaxf(m[5], c.y);
        m[6] = fmaxf(m[6], c.z); m[7] = fmaxf(m[7], c.w);
    }
    float s = 0.0f;
    #pragma unroll
    for (int j = 0; j < 8; j++) s += m[j] * rd_adapt(wd, c0 + j, isbf);
    #pragma unroll
    for (int o = 32; o > 0; o >>= 1) s += __shfl_down(s, o);
    __shared__ float sa[3];
    int lane = tid & 63, wv = tid >> 6;
    if (lane == 0) sa[wv] = s;
    __syncthreads();
    if (tid == 0) {
        float r = sa[0] + sa[1] + sa[2] + rd_adapt(bd, 0, isbf);
        if (isbf) ((bf16_t*)out)[b] = (bf16_t)r;
        else      ((float*)out)[b]  = r;
    }
}

// ---------------------------------------------------------------------------
extern "C" void kernel_launch(void* const* d_in, const int* in_sizes, int n_in,
                              void* d_out, int out_size, void* d_ws, size_t ws_size,
                              hipStream_t stream)
{
    const void* embed = d_in[0];
    const void* wq  = d_in[1];  const void* bq  = d_in[2];
    const void* wk  = d_in[3];  const void* bk  = d_in[4];
    const void* wv  = d_in[5];  const void* bv  = d_in[6];
    const void* dw  = d_in[7];  const void* pw  = d_in[8];  const void* sep_b = d_in[9];
    const void* wck = d_in[10]; const void* bck = d_in[11];
    const void* wco = d_in[12]; const void* bco = d_in[13];
    const void* wso = d_in[14]; const void* bso = d_in[15];
    const void* ln1g = d_in[16]; const void* ln1b = d_in[17];
    const void* wi  = d_in[18]; const void* bi  = d_in[19];
    const void* wo  = d_in[20]; const void* bo  = d_in[21];
    const void* ln2g = d_in[22]; const void* ln2b = d_in[23];
    const void* wd  = d_in[24]; const void* bd  = d_in[25];
    (void)ws_size; (void)in_sizes; (void)n_in; (void)out_size;

    // ---- arena (143.2 MB), lifetime-aliased ----
    char* ws = (char*)d_ws;
    char* A  = ws;                          // 50.33 MB: qkvco -> ybuf/interb/lout
    char* B  = ws + 50331648;               // 25.17 MB: wT_all -> dconvb -> ckb -> vT -> wiT+woT
    char* C_ = ws + 75497472;               // 12.58 MB: sepb -> mpart
    char* D  = ws + 88080384;               // 25.17 MB: ctxcat -> attn
    char* E  = ws + 113246208;              // 25.17 MB: ebuf -> y2
    char* F  = ws + 138412032;              //  4.72 MB: pwT+wckT -> wsoT
    char* XP = ws + 143130624;              //  flag + cbias + dwT

    bf16_t* qkvco  = (bf16_t*)A;                    // [8192,3072]
    bf16_t* ybuf   = (bf16_t*)A;                    // [8192,1536] (after flash)
    bf16_t* interb = (bf16_t*)A;                    // [8192,3072] (after ln1)
    bf16_t* lout   = (bf16_t*)A;                    // [8192,1536] (after wo)
    bf16_t* wT_all = (bf16_t*)B;                    // [3072,1536] (merged gemm)
    bf16_t* dconvb = (bf16_t*)B;                    // [8192,1536] (after merged)
    bf16_t* ckb    = (bf16_t*)B;                    // [8192,64]   (after sep)
    bf16_t* vT     = (bf16_t*)B;                    // [8,768,1024] (after conv_out)
    bf16_t* wiT    = (bf16_t*)B;                    // [3072,1536] (after flash)
    bf16_t* woT    = (bf16_t*)(B + 9437184);        // [1536,3072] (after flash)
    bf16_t* sepb   = (bf16_t*)C_;                   // [8192,768]
    float*  mpart  = (float*)C_;                    // [8,32,1536] f32
    bf16_t* ctxcat = (bf16_t*)D;                    // [8192,1536]
    bf16_t* attn   = (bf16_t*)D;                    // [8192,1536]
    bf16_t* ebuf   = (bf16_t*)E;                    // [8192,1536]
    bf16_t* y2     = (bf16_t*)E;                    // [8192,1536]
    bf16_t* pwT    = (bf16_t*)F;                    // [768,1536]
    bf16_t* wckT   = (bf16_t*)(F + 2359296);        // [128,768]
    bf16_t* wsoT   = (bf16_t*)F;                    // [1536,1536] (after ck gemm)
    int*    flag   = (int*)XP;
    bf16_t* cbias  = (bf16_t*)(XP + 256);           // [3072]
    float*  dwT    = (float*)(XP + 8192);           // [7,1536] f32

    dim3 blk(256);

    // big GEMMs: 256x256 pipelined (M%256==0, N%256==0, Kd%128==0)
    auto gemm_big = [&](const bf16_t* Ai, const bf16_t* Bt, bf16_t* Ci, const void* bias,
                        const bf16_t* resi, int ldr, const bf16_t* emul, int lde,
                        const int* fl, int M, int N, int Kd, int lda, int ldb, int ldc,
                        int act) {
        int tn = N / 256;
        dim3 g((M / 256) * tn);
        gemm256<<<g, dim3(512), 0, stream>>>(Ai, Bt, Ci, bias, resi, ldr, emul, lde, fl,
                                             M, N, Kd, lda, ldb, ldc, act, tn);
    };
    // legacy 128x128 path (sep + ck GEMM)
    auto gemm = [&](const bf16_t* Ai, const bf16_t* Bt, bf16_t* Ci, const void* bias,
                    long long biasOff, const bf16_t* emul, int lde, const int* fl,
                    int M, int N, int Kd, int lda, int ldb, int ldc,
                    float scale, int act, int beta, int nlim) {
        dim3 g(M / 128, (N + 127) / 128, 1);
        gemm_tile<<<g, blk, 0, stream>>>(Ai, Bt, Ci, bias, biasOff, emul, lde, fl,
                                         M, N, Kd, lda, ldb, ldc,
                                         scale, act, beta, nlim);
    };

    // --- dtype probe, weight prep (one launch), embed conversion ---
    detect_kernel<<<dim3(1), blk, 0, stream>>>(embed, flag);
    prep_weights<<<dim3(1518), blk, 0, stream>>>(wq, wk, wv, wco, pw, wck, dw,
                                                 bq, bk, bv, bco,
                                                 wT_all, pwT, wckT, dwT, cbias, flag);
    convert_embed<<<dim3(6144), blk, 0, stream>>>(embed, ebuf, flag);

    // --- merged Q|K|V|co projection ---
    gemm_big(ebuf, wT_all, qkvco, cbias, nullptr, 0, nullptr, 0, nullptr,
             8192, 3072, 1536, HH, HH, 3072, 0);

    // --- separable conv: depthwise (vectorized), pointwise fused with *q ---
    dconv_kernel<<<dim3((BB * SS * 192) / 256), blk, 0, stream>>>(ebuf, dwT, dconvb);
    gemm(dconvb, pwT, sepb, sep_b, 0, qkvco, 3072, flag,
         8192, 768, 1536, HH, HH, AHH, 1.0f, 0, 0, 767);

    // --- span conv kernels (ck scores -> softmax inline in conv_out) ---
    gemm(sepb, wckT, ckb, bck, 0, nullptr, 0, flag,
         8192, 56, 768, AHH, AHH, 64, 1.0f, 0, 0, 127);
    conv_out_kernel<<<dim3((BB * SS * 96) / 256), blk, 0, stream>>>(qkvco + 2304, 3072, ckb, ctxcat);

    // --- fused flash attention (XCD-local grid: bh fastest) ---
    transpose_v8<<<dim3(12, 16, 8), blk, 0, stream>>>(qkvco, vT, 1024, 768, 3072, 1536,
                                                      1024ll * 3072, 768ll * 1024, nullptr);
    flash_attn<<<dim3(64, 8), blk, 0, stream>>>(qkvco, vT, ctxcat);

    // --- late weight prep (one launch; B slot free after flash) ---
    prep_late<<<dim3(2880), blk, 0, stream>>>(wso, wi, wo, wsoT, wiT, woT, flag);

    // --- self output (+embed residual fused) + LN1 ---
    gemm_big(ctxcat, wsoT, ybuf, bso, ebuf, HH, nullptr, 0, flag,
             8192, 1536, 1536, HH, HH, HH, 0);
    ln_kernel<<<dim3(8192), dim3(192), 0, stream>>>(ybuf, ln1g, ln1b, attn, flag);

    // --- FFN full-width (+attn residual fused in wo) + LN2 ---
    gemm_big(attn, wiT, interb, bi, nullptr, 0, nullptr, 0, flag,
             8192, 3072, 1536, HH, HH, IMM, 1);
    gemm_big(interb, woT, y2, bo, attn, HH, nullptr, 0, flag,
             8192, 1536, 3072, IMM, IMM, HH, 0);
    ln_kernel<<<dim3(8192), dim3(192), 0, stream>>>(y2, ln2g, ln2b, lout, flag);

    // --- pool + decode (partials in dead sepb slot) ---
    maxpool_p1<<<dim3(32, 8), dim3(192), 0, stream>>>(lout, mpart);
    pool_decode<<<dim3(BB), dim3(192), 0, stream>>>(mpart, wd, bd, d_out, flag);
}

// Round 7
// 840.296 us; speedup vs baseline: 1.0455x; 1.0455x over previous
//
#include <hip/hip_runtime.h>

// ---------------------------------------------------------------------------
// ConvBERT layer forward, bf16 compute / fp32 accumulate.
// B=8 S=1024 H=1536 NH=8 HD=96 AH=768 K=7 IM=3072
// Round 14: revert the residual-in-epilogue fusion (scalar scattered resi
//           reads cost more than the LN pass they saved — counters r6);
//           ln_kernel back to 2-input. Route the N=1536 GEMMs (wso, wo)
//           through the 128x128 gemm_tile (768 WGs = 3 full rounds, no CU
//           quantization loss) instead of gemm256 (192 WGs = 75% util).
//           Keep prep_weights/prep_late consolidation + ck-softmax fold.
// ---------------------------------------------------------------------------

typedef __bf16 bf16_t;
typedef short s16x8 __attribute__((ext_vector_type(8)));   // 8 bf16 in 4 VGPRs
typedef float f32x4 __attribute__((ext_vector_type(4)));

#define BB  8
#define SS  1024
#define HH  1536
#define NHH 8
#define HDD 96
#define AHH 768
#define IMM 3072

__device__ __forceinline__ float rd_adapt(const void* p, long long i, int isbf) {
    return isbf ? (float)((const bf16_t*)p)[i] : ((const float*)p)[i];
}
// bf16 bits -> f32 (bf16 is upper 16 bits of f32)
__device__ __forceinline__ float bs2f(short x) {
    return __uint_as_float(((unsigned)(unsigned short)x) << 16);
}
// f32 -> bf16 bits (RNE via hardware cvt)
__device__ __forceinline__ short f2bs(float f) {
    bf16_t b = (bf16_t)f; short s; __builtin_memcpy(&s, &b, 2); return s;
}

// tanh-form GELU: max |diff| vs exact erf-GELU ~3e-3, far under bf16 budget
__device__ __forceinline__ float gelu_f(float v) {
    float u = v * (0.7978845608f + 0.0356774081f * v * v);
    float e = __expf(2.0f * u);
    float t = 1.0f - 2.0f / (e + 1.0f);
    return 0.5f * v * (1.0f + t);
}

// async global->LDS, 16B per lane; lds base must be wave-uniform
__device__ __forceinline__ void gl2lds16(const bf16_t* g, bf16_t* l) {
    __builtin_amdgcn_global_load_lds(
        (__attribute__((address_space(1))) const void*)g,
        (__attribute__((address_space(3))) void*)l, 16, 0, 0);
}

#define FENCE() asm volatile("" ::: "memory")
#define BARRIER() do { FENCE(); __builtin_amdgcn_s_barrier(); FENCE(); } while (0)
#define LGKM(n) asm volatile("s_waitcnt lgkmcnt(" #n ")" ::: "memory")
#define VMCNT(n) asm volatile("s_waitcnt vmcnt(" #n ")" ::: "memory")
#define SCHEDB() __builtin_amdgcn_sched_barrier(0)
#define PRIO(n) __builtin_amdgcn_s_setprio(n)
#define RDV(base, imm) (*(const s16x8*)(smb + (base) + (imm)))

#define MFMA_CLUSTER(AF, BF, IO, JO)                                            \
    _Pragma("unroll")                                                           \
    for (int i_ = 0; i_ < 4; i_++)                                              \
        _Pragma("unroll")                                                       \
        for (int j_ = 0; j_ < 2; j_++) {                                        \
            acc[(IO)+i_][(JO)+j_] = __builtin_amdgcn_mfma_f32_16x16x32_bf16(    \
                AF[i_][0], BF[j_][0], acc[(IO)+i_][(JO)+j_], 0, 0, 0);          \
            acc[(IO)+i_][(JO)+j_] = __builtin_amdgcn_mfma_f32_16x16x32_bf16(    \
                AF[i_][1], BF[j_][1], acc[(IO)+i_][(JO)+j_], 0, 0, 0);          \
        }

// ---------------------------------------------------------------------------
// dtype probe: bf16 vs fp32 inputs. flag=1 -> bf16.
// ---------------------------------------------------------------------------
__global__ __launch_bounds__(256)
void detect_kernel(const void* __restrict__ embed, int* __restrict__ flag)
{
    __shared__ int cnt[256];
    int t = threadIdx.x;
    float x = (float)((const bf16_t*)embed)[t];
    float a = fabsf(x);
    cnt[t] = (a > 1e-3f && a < 50.0f) ? 1 : 0;
    __syncthreads();
    for (int o = 128; o > 0; o >>= 1) { if (t < o) cnt[t] += cnt[t + o]; __syncthreads(); }
    if (t == 0) *flag = (cnt[0] >= 205) ? 1 : 0;
}

__global__ __launch_bounds__(256)
void convert_embed(const void* __restrict__ in, bf16_t* __restrict__ out,
                   const int* __restrict__ flagp)
{
    int isbf = *flagp;
    long long i0 = ((long long)blockIdx.x * 256 + threadIdx.x) * 8;
    if (isbf) {
        *(s16x8*)(out + i0) = *(const s16x8*)((const bf16_t*)in + i0);
    } else {
        const float* f = (const float*)in;
        #pragma unroll
        for (int j = 0; j < 8; j++) out[i0 + j] = (bf16_t)f[i0 + j];
    }
}

// ---------------------------------------------------------------------------
// Generic 64x64 transpose tile body (shared-mem staged, 16B in / 16B out).
// ---------------------------------------------------------------------------
__device__ __forceinline__ void tr64_body(const void* in, bf16_t* out,
                                          int C, int ldin, int R,
                                          int cb, int rb, int isbf,
                                          bf16_t (*t)[72])
{
    int tr = threadIdx.x >> 3;           // 0..31
    int tc = (threadIdx.x & 7) * 8;      // 0..56
    #pragma unroll
    for (int it = 0; it < 2; it++) {
        int r = tr + it * 32;
        int gc = cb + tc;
        if (isbf && gc + 8 <= C) {
            *(s16x8*)&t[r][tc] =
                *(const s16x8*)((const bf16_t*)in + (long long)(rb + r) * ldin + gc);
        } else {
            #pragma unroll
            for (int j = 0; j < 8; j++)
                t[r][tc + j] = (gc + j < C)
                    ? (bf16_t)rd_adapt(in, (long long)(rb + r) * ldin + gc + j, isbf)
                    : (bf16_t)0.0f;
        }
    }
    __syncthreads();
    int oc = threadIdx.x >> 2;           // 0..63
    int r0 = (threadIdx.x & 3) * 16;
    s16x8 v0, v1;
    #pragma unroll
    for (int j = 0; j < 8; j++) v0[j] = *(short*)&t[r0 + j][oc];
    #pragma unroll
    for (int j = 0; j < 8; j++) v1[j] = *(short*)&t[r0 + 8 + j][oc];
    bf16_t* dst = out + (long long)(cb + oc) * R + rb + r0;
    *(s16x8*)dst = v0;
    *(s16x8*)(dst + 8) = v1;
}

// ---------------------------------------------------------------------------
// prep_weights: one launch for all early weight prep.
// ---------------------------------------------------------------------------
__global__ __launch_bounds__(256)
void prep_weights(const void* __restrict__ wq, const void* __restrict__ wk,
                  const void* __restrict__ wv, const void* __restrict__ wco,
                  const void* __restrict__ pw, const void* __restrict__ wck,
                  const void* __restrict__ dw,
                  const void* __restrict__ b0, const void* __restrict__ b1,
                  const void* __restrict__ b2, const void* __restrict__ b3,
                  bf16_t* __restrict__ wT_all, bf16_t* __restrict__ pwT,
                  bf16_t* __restrict__ wckT, float* __restrict__ dwT,
                  bf16_t* __restrict__ cbias, const int* __restrict__ flagp)
{
    __shared__ bf16_t t[64][72];
    int isbf = *flagp;
    int j = blockIdx.x;
    if (j < 1152) {
        int z = j / 288, rm = j % 288;
        const void* in = (z == 0) ? wq : (z == 1) ? wk : (z == 2) ? wv : wco;
        tr64_body(in, wT_all + (long long)z * 768 * 1536, 768, 768, 1536,
                  (rm % 12) * 64, (rm / 12) * 64, isbf, t);
    } else if (j < 1440) {
        int rm = j - 1152;
        tr64_body(pw, pwT, 768, 768, 1536, (rm % 12) * 64, (rm / 12) * 64, isbf, t);
    } else if (j < 1464) {
        int rm = j - 1440;
        tr64_body(wck, wckT, 56, 56, 768, (rm % 2) * 64, (rm / 2) * 64, isbf, t);
    } else if (j < 1506) {
        int idx = (j - 1464) * 256 + threadIdx.x;     // < 10752 exactly
        int k = idx % 7, c = idx / 7;
        dwT[k * HH + c] = rd_adapt(dw, (long long)c * 7 + k, isbf);
    } else {
        int tt = (j - 1506) * 256 + threadIdx.x;      // < 3072
        int sel = tt / 768, off = tt - sel * 768;
        const void* src = (sel == 0) ? b0 : (sel == 1) ? b1 : (sel == 2) ? b2 : b3;
        cbias[tt] = (bf16_t)rd_adapt(src, off, isbf);
    }
}

// ---------------------------------------------------------------------------
// prep_late: wsoT + wiT + woT in one launch (runs after flash frees B slot).
// ---------------------------------------------------------------------------
__global__ __launch_bounds__(256)
void prep_late(const void* __restrict__ wso, const void* __restrict__ wi,
               const void* __restrict__ wo, bf16_t* __restrict__ wsoT,
               bf16_t* __restrict__ wiT, bf16_t* __restrict__ woT,
               const int* __restrict__ flagp)
{
    __shared__ bf16_t t[64][72];
    int isbf = *flagp;
    int j = blockIdx.x;
    if (j < 576) {
        tr64_body(wso, wsoT, 1536, 1536, 1536, (j % 24) * 64, (j / 24) * 64, isbf, t);
    } else if (j < 1728) {
        int rm = j - 576;
        tr64_body(wi, wiT, 3072, 3072, 1536, (rm % 48) * 64, (rm / 48) * 64, isbf, t);
    } else {
        int rm = j - 1728;
        tr64_body(wo, woT, 1536, 1536, 3072, (rm % 24) * 64, (rm / 24) * 64, isbf, t);
    }
}

// ---------------------------------------------------------------------------
// gemm256 v3 (frozen loop): 256x256 tile, BK=64, 512 thr = 8 waves (2M x 4N).
// ---------------------------------------------------------------------------
template<int IB, int OB>
__device__ __forceinline__ void tile_step(
    char* smb, int vA0, int vA1, int vB0, int vB1,
    const char* gA00, const char* gA01, const char* gA10, const char* gA11,
    const char* gB00, const char* gB01, const char* gB10, const char* gB11,
    char* ldsAw, char* ldsBw, int k1, int k2,
    s16x8 (&af0)[4][2], s16x8 (&af1)[4][2],
    s16x8 (&bf0)[2][2], s16x8 (&bf1)[2][2],
    f32x4 (&acc)[8][4])
{
    // ---- phase 1: MFMA af0 x bf0; issue bf1 reads; stage A-h1(t+1)->OB ----
    BARRIER();
    bf1[0][0] = RDV(vB0, IB + 4096); bf1[0][1] = RDV(vB1, IB + 4096);
    bf1[1][0] = RDV(vB0, IB + 6144); bf1[1][1] = RDV(vB1, IB + 6144);
    gl2lds16((const bf16_t*)(gA10 + k1), (bf16_t*)(ldsAw + OB + 16384));
    gl2lds16((const bf16_t*)(gA11 + k1), (bf16_t*)(ldsAw + OB + 17408));
    LGKM(4); SCHEDB(); PRIO(1);
    MFMA_CLUSTER(af0, bf0, 0, 0);
    PRIO(0);

    // ---- phase 2: MFMA af0 x bf1; issue af1 reads; stage B-h1(t+1)->OB ----
    BARRIER();
    af1[0][0] = RDV(vA0, IB + 8192);  af1[0][1] = RDV(vA1, IB + 8192);
    af1[1][0] = RDV(vA0, IB + 10240); af1[1][1] = RDV(vA1, IB + 10240);
    af1[2][0] = RDV(vA0, IB + 12288); af1[2][1] = RDV(vA1, IB + 12288);
    af1[3][0] = RDV(vA0, IB + 14336); af1[3][1] = RDV(vA1, IB + 14336);
    gl2lds16((const bf16_t*)(gB10 + k1), (bf16_t*)(ldsBw + OB + 16384));
    gl2lds16((const bf16_t*)(gB11 + k1), (bf16_t*)(ldsBw + OB + 17408));
    LGKM(8); SCHEDB(); PRIO(1);
    MFMA_CLUSTER(af0, bf1, 0, 2);
    PRIO(0);

    // ---- phase 3: MFMA af1 x bf1; stage B-h0 + A-h0 (t+2)->IB ----
    BARRIER();
    gl2lds16((const bf16_t*)(gB00 + k2), (bf16_t*)(ldsBw + IB));
    gl2lds16((const bf16_t*)(gB01 + k2), (bf16_t*)(ldsBw + IB + 1024));
    gl2lds16((const bf16_t*)(gA00 + k2), (bf16_t*)(ldsAw + IB));
    gl2lds16((const bf16_t*)(gA01 + k2), (bf16_t*)(ldsAw + IB + 1024));
    LGKM(0); SCHEDB(); PRIO(1);
    MFMA_CLUSTER(af1, bf1, 4, 2);
    PRIO(0);

    // ---- phase 4: t+1 landed; MFMA af1 x bf0; preload af0'/bf0' from OB ----
    VMCNT(4);
    BARRIER();
    af0[0][0] = RDV(vA0, OB + 0);    af0[0][1] = RDV(vA1, OB + 0);
    af0[1][0] = RDV(vA0, OB + 2048); af0[1][1] = RDV(vA1, OB + 2048);
    af0[2][0] = RDV(vA0, OB + 4096); af0[2][1] = RDV(vA1, OB + 4096);
    af0[3][0] = RDV(vA0, OB + 6144); af0[3][1] = RDV(vA1, OB + 6144);
    PRIO(1);
    MFMA_CLUSTER(af1, bf0, 4, 0);
    PRIO(0);
    bf0[0][0] = RDV(vB0, OB + 0);    bf0[0][1] = RDV(vB1, OB + 0);
    bf0[1][0] = RDV(vB0, OB + 2048); bf0[1][1] = RDV(vB1, OB + 2048);
}

__global__ __launch_bounds__(512, 2)
void gemm256(const bf16_t* __restrict__ A, const bf16_t* __restrict__ Bt,
             bf16_t* __restrict__ C, const void* __restrict__ bias,
             const bf16_t* __restrict__ emul, int lde, const int* __restrict__ flagp,
             int M, int N, int Kd, int lda, int ldb, int ldc, int act, int tilesN)
{
    __shared__ bf16_t Sm[65536];   // 128 KiB
    char* smb = (char*)Sm;
    int isbf = flagp ? *flagp : 1;

    // bijective XCD remap (m204) of the linear tile id; n fastest inside
    int nwg = gridDim.x;
    int orig = blockIdx.x;
    int q = nwg >> 3, r = nwg & 7;
    int xcd = orig & 7, lid = orig >> 3;
    int wg = (xcd < r ? xcd * (q + 1) : r * (q + 1) + (xcd - r) * q) + lid;
    int row0 = (wg / tilesN) * 256;
    int col0 = (wg % tilesN) * 256;

    int tid = threadIdx.x;
    int wave = tid >> 6, lane = tid & 63;
    int wm = wave >> 2, wn = wave & 3;
    int lm = lane & 15, kq = lane >> 4;

    // ---- staging geometry: wave w loads chunks {2w,2w+1} of each 16KB half
    int srow = lane >> 3;                       // 0..7 row within 1KB chunk
    int scol = 8 * ((lane & 7) ^ srow);         // pre-swizzled source col (bf16)

    // per-lane global byte bases [h][l]
    const char* gA00 = (const char*)(A + (long long)(row0 +   0 + (2*wave + 0)*8 + srow) * lda + scol);
    const char* gA01 = (const char*)(A + (long long)(row0 +   0 + (2*wave + 1)*8 + srow) * lda + scol);
    const char* gA10 = (const char*)(A + (long long)(row0 + 128 + (2*wave + 0)*8 + srow) * lda + scol);
    const char* gA11 = (const char*)(A + (long long)(row0 + 128 + (2*wave + 1)*8 + srow) * lda + scol);
    const char* gB00 = (const char*)(Bt + (long long)(col0 +   0 + (2*wave + 0)*8 + srow) * ldb + scol);
    const char* gB01 = (const char*)(Bt + (long long)(col0 +   0 + (2*wave + 1)*8 + srow) * ldb + scol);
    const char* gB10 = (const char*)(Bt + (long long)(col0 + 128 + (2*wave + 0)*8 + srow) * ldb + scol);
    const char* gB11 = (const char*)(Bt + (long long)(col0 + 128 + (2*wave + 1)*8 + srow) * ldb + scol);

    // wave-uniform LDS staging bases
    char* ldsAw = smb + 2 * wave * 1024;            // A region
    char* ldsBw = smb + 65536 + 2 * wave * 1024;    // B region

    // ---- fragment-read base vaddrs (swizzled); all reads = vaddr + imm ----
    int xo = (lm & 7) << 4;
    int c0 = (kq * 16) ^ xo;
    int c1 = (64 + kq * 16) ^ xo;
    int vA0 = (wm * 128 + lm) * 128 + c0;
    int vA1 = (wm * 128 + lm) * 128 + c1;
    int vB0 = 65536 + (wn * 64 + lm) * 128 + c0;
    int vB1 = 65536 + (wn * 64 + lm) * 128 + c1;

    f32x4 acc[8][4] = {};
    s16x8 af0[4][2], af1[4][2], bf0[2][2], bf1[2][2];

    int KT = Kd >> 6;
    int KTm1 = KT - 1;

    // ---- prologue: tile0 all 4 halves + tile1 B-h0/A-h0 ----
    gl2lds16((const bf16_t*)gA00, (bf16_t*)(ldsAw));
    gl2lds16((const bf16_t*)gA01, (bf16_t*)(ldsAw + 1024));
    gl2lds16((const bf16_t*)gA10, (bf16_t*)(ldsAw + 16384));
    gl2lds16((const bf16_t*)gA11, (bf16_t*)(ldsAw + 17408));
    gl2lds16((const bf16_t*)gB00, (bf16_t*)(ldsBw));
    gl2lds16((const bf16_t*)gB01, (bf16_t*)(ldsBw + 1024));
    gl2lds16((const bf16_t*)gB10, (bf16_t*)(ldsBw + 16384));
    gl2lds16((const bf16_t*)gB11, (bf16_t*)(ldsBw + 17408));
    int kb1 = min(1, KTm1) << 7;
    gl2lds16((const bf16_t*)(gB00 + kb1), (bf16_t*)(ldsBw + 32768));
    gl2lds16((const bf16_t*)(gB01 + kb1), (bf16_t*)(ldsBw + 33792));
    gl2lds16((const bf16_t*)(gA00 + kb1), (bf16_t*)(ldsAw + 32768));
    gl2lds16((const bf16_t*)(gA01 + kb1), (bf16_t*)(ldsAw + 33792));
    VMCNT(4);
    BARRIER();
    // R1(0): af0 + bf0 from buf0
    af0[0][0] = RDV(vA0, 0);    af0[0][1] = RDV(vA1, 0);
    af0[1][0] = RDV(vA0, 2048); af0[1][1] = RDV(vA1, 2048);
    af0[2][0] = RDV(vA0, 4096); af0[2][1] = RDV(vA1, 4096);
    af0[3][0] = RDV(vA0, 6144); af0[3][1] = RDV(vA1, 6144);
    bf0[0][0] = RDV(vB0, 0);    bf0[0][1] = RDV(vB1, 0);
    bf0[1][0] = RDV(vB0, 2048); bf0[1][1] = RDV(vB1, 2048);

    for (int it = 0; it < (KT >> 1); ++it) {
        int t = it << 1;
        int k1 = min(t + 1, KTm1) << 7;
        int k2 = min(t + 2, KTm1) << 7;
        int k3 = min(t + 3, KTm1) << 7;
        tile_step<0, 32768>(smb, vA0, vA1, vB0, vB1,
                            gA00, gA01, gA10, gA11, gB00, gB01, gB10, gB11,
                            ldsAw, ldsBw, k1, k2, af0, af1, bf0, bf1, acc);
        tile_step<32768, 0>(smb, vA0, vA1, vB0, vB1,
                            gA00, gA01, gA10, gA11, gB00, gB01, gB10, gB11,
                            ldsAw, ldsBw, k2, k3, af0, af1, bf0, bf1, acc);
    }

    // ---- epilogue: D row = kq*4 + r, col = lm (m89/m91-verified) ----
    #pragma unroll
    for (int j = 0; j < 4; j++) {
        int gcol = col0 + wn * 64 + j * 16 + lm;
        float bv = bias ? rd_adapt(bias, gcol, isbf) : 0.0f;
        #pragma unroll
        for (int ip = 0; ip < 8; ip++) {
            int grow0 = row0 + wm * 128 + ip * 16 + kq * 4;
            #pragma unroll
            for (int r = 0; r < 4; r++) {
                float v = acc[ip][j][r] + bv;
                if (emul) v *= (float)emul[(long long)(grow0 + r) * lde + gcol];
                if (act) v = gelu_f(v);
                C[(long long)(grow0 + r) * ldc + gcol] = (bf16_t)v;
            }
        }
    }
}

// ---------------------------------------------------------------------------
// 128x128 GEMM (sep + ck + wso + wo).
// ---------------------------------------------------------------------------
__global__ __launch_bounds__(256)
void gemm_tile(const bf16_t* __restrict__ A, const bf16_t* __restrict__ Bt,
               bf16_t* __restrict__ C, const void* __restrict__ bias, long long biasOff,
               const bf16_t* __restrict__ emul, int lde, const int* __restrict__ flagp,
               int M, int N, int Kd, int lda, int ldb, int ldc,
               float scale, int act, int beta, int nlim)
{
    __shared__ bf16_t Sm[16384];   // As: [2][128][32] at 0; Bs: [2][128][32] at 8192

    int isbf = flagp ? *flagp : 1;
    int tid  = threadIdx.x;
    int wave = tid >> 6, lane = tid & 63;
    int wm = wave >> 1, wn = wave & 1;
    int row0 = blockIdx.x * 128;
    int col0 = blockIdx.y * 128;
    int lm = lane & 15;
    int kq = lane >> 4;

    int sr = tid >> 2;            // 0..63
    int sc = (tid & 3) * 8;       // 0,8,16,24
    const bf16_t* ga0 = A + (long long)(row0 + sr) * lda + sc;
    const bf16_t* ga1 = A + (long long)(row0 + 64 + sr) * lda + sc;
    int br0 = min(col0 + sr, nlim);
    int br1 = min(col0 + 64 + sr, nlim);
    const bf16_t* gb0 = Bt + (long long)br0 * ldb + sc;
    const bf16_t* gb1 = Bt + (long long)br1 * ldb + sc;
    bf16_t* lw = Sm + wave * 512;   // wave-uniform staging base

    f32x4 acc[4][4] = {};

    for (int k0 = 0; k0 < Kd; k0 += 64) {
        #pragma unroll
        for (int h = 0; h < 2; h++) {
            int kh = k0 + h * 32;
            gl2lds16(ga0 + kh, lw + h * 4096);
            gl2lds16(ga1 + kh, lw + h * 4096 + 2048);
            gl2lds16(gb0 + kh, lw + 8192 + h * 4096);
            gl2lds16(gb1 + kh, lw + 8192 + h * 4096 + 2048);
        }
        __syncthreads();

        s16x8 af[2][4], bfr[2][4];
        #pragma unroll
        for (int h = 0; h < 2; h++) {
            #pragma unroll
            for (int i = 0; i < 4; i++)
                af[h][i] = *(const s16x8*)(Sm + h * 4096 + (wm * 64 + i * 16 + lm) * 32 + kq * 8);
            #pragma unroll
            for (int j = 0; j < 4; j++)
                bfr[h][j] = *(const s16x8*)(Sm + 8192 + h * 4096 + (wn * 64 + j * 16 + lm) * 32 + kq * 8);
        }
        #pragma unroll
        for (int i = 0; i < 4; i++)
            #pragma unroll
            for (int j = 0; j < 4; j++) {
                acc[i][j] = __builtin_amdgcn_mfma_f32_16x16x32_bf16(af[0][i], bfr[0][j], acc[i][j], 0, 0, 0);
                acc[i][j] = __builtin_amdgcn_mfma_f32_16x16x32_bf16(af[1][i], bfr[1][j], acc[i][j], 0, 0, 0);
            }
        __syncthreads();
    }

    // epilogue: D row = kq*4 + r, col = lm (m89/m91-verified)
    #pragma unroll
    for (int j = 0; j < 4; j++) {
        int gcol = col0 + wn * 64 + j * 16 + lm;
        if (gcol >= N) continue;
        float bv = bias ? rd_adapt(bias, biasOff + gcol, isbf) : 0.0f;
        #pragma unroll
        for (int i = 0; i < 4; i++) {
            int grow0 = row0 + wm * 64 + i * 16 + kq * 4;
            #pragma unroll
            for (int r = 0; r < 4; r++) {
                float v = acc[i][j][r] * scale + bv;
                long long ci = (long long)(grow0 + r) * ldc + gcol;
                if (beta) v += (float)C[ci];
                if (emul) v *= (float)emul[(long long)(grow0 + r) * lde + gcol];
                if (act) v = gelu_f(v);
                C[ci] = (bf16_t)v;
            }
        }
    }
}

// ---------------------------------------------------------------------------
// Fused flash attention. grid = (64 bh, 8 q-tiles), block = 256.
// K-tile staged once per block into swizzled LDS [3][128][32].
// ---------------------------------------------------------------------------
__global__ __launch_bounds__(256, 2)
void flash_attn(const bf16_t* __restrict__ qkv, const bf16_t* __restrict__ vT,
                bf16_t* __restrict__ ctxcat)
{
    const float ascale = 0.1020620726159658f;   // 1/sqrt(96)
    __shared__ bf16_t KL[12288];                // K tile [3][128][32] swizzled, 24KB
    __shared__ bf16_t Pl[4 * 32 * 136];         // per-wave P[32][136] (pad 8)

    int bh = blockIdx.x;
    int b = bh >> 3, h = bh & 7;
    const bf16_t* Qp = qkv  + (long long)b * SS * 3072 + h * HDD;
    const bf16_t* Kp = qkv  + (long long)b * SS * 3072 + 768 + h * HDD;
    const bf16_t* Vt = vT   + (long long)b * AHH * SS + (long long)h * HDD * SS;
    bf16_t*       Op = ctxcat + (long long)b * SS * HH + h * HDD;

    int tid = threadIdx.x, wave = tid >> 6, lane = tid & 63;
    int lm = lane & 15, kq = lane >> 4;
    int q0 = blockIdx.y * 128 + wave * 32;
    bf16_t* Pw = Pl + wave * 32 * 136;

    // ---- K staging: 24 chunks of 1KB (chunk = 16 rows of [32-feat] block).
    int srow_l = lane >> 2;                                   // 0..15
    int sslot  = ((lane & 3) ^ ((lane >> 3) & 3)) * 8;        // logical col (elem)
    auto stageK = [&](int kt) {
        #pragma unroll
        for (int i = 0; i < 6; i++) {
            int qc = wave + 4 * i;                            // 0..23
            int fb = qc >> 3, cc = qc & 7;
            gl2lds16(Kp + (long long)(kt * 128 + cc * 16 + srow_l) * 3072 + fb * 32 + sslot,
                     KL + qc * 512);
        }
    };
    const char* klb = (const char*)KL + lm * 64 + ((kq ^ ((lm >> 1) & 3)) << 4);

    s16x8 aq[2][3];
    #pragma unroll
    for (int i = 0; i < 2; i++)
        #pragma unroll
        for (int kf = 0; kf < 3; kf++)
            aq[i][kf] = *(const s16x8*)(Qp + (long long)(q0 + i * 16 + lm) * 3072 + kf * 32 + kq * 8);

    stageK(0);
    __syncthreads();

    f32x4 Oacc[2][6] = {};
    float mrow[2][4], lrow[2][4];
    #pragma unroll
    for (int i = 0; i < 2; i++)
        #pragma unroll
        for (int r = 0; r < 4; r++) { mrow[i][r] = -1e30f; lrow[i][r] = 0.0f; }

    for (int kt = 0; kt < 8; kt++) {
        f32x4 S[2][8] = {};
        #pragma unroll
        for (int j = 0; j < 8; j++) {
            s16x8 bk[3];
            #pragma unroll
            for (int kf = 0; kf < 3; kf++)
                bk[kf] = *(const s16x8*)(klb + kf * 8192 + j * 1024);
            #pragma unroll
            for (int i = 0; i < 2; i++)
                #pragma unroll
                for (int kf = 0; kf < 3; kf++)
                    S[i][j] = __builtin_amdgcn_mfma_f32_16x16x32_bf16(aq[i][kf], bk[kf], S[i][j], 0, 0, 0);
        }
        __syncthreads();                     // all waves done reading KL
        if (kt < 7) stageK(kt + 1);          // overwrite KL; lands under softmax+PV

        float mnew[2][4];
        #pragma unroll
        for (int i = 0; i < 2; i++) {
            #pragma unroll
            for (int r = 0; r < 4; r++) {
                float mx = -1e30f;
                #pragma unroll
                for (int j = 0; j < 8; j++) mx = fmaxf(mx, S[i][j][r]);
                #pragma unroll
                for (int msk = 1; msk <= 8; msk <<= 1) mx = fmaxf(mx, __shfl_xor(mx, msk));
                mnew[i][r] = fmaxf(mrow[i][r], mx * ascale);
            }
        }
        #pragma unroll
        for (int i = 0; i < 2; i++) {
            #pragma unroll
            for (int r = 0; r < 4; r++) {
                float al = __expf(mrow[i][r] - mnew[i][r]);
                lrow[i][r] *= al;
                #pragma unroll
                for (int n = 0; n < 6; n++) Oacc[i][n][r] *= al;
                mrow[i][r] = mnew[i][r];
            }
        }
        float psum[2][4] = {};
        #pragma unroll
        for (int i = 0; i < 2; i++) {
            #pragma unroll
            for (int j = 0; j < 8; j++) {
                #pragma unroll
                for (int r = 0; r < 4; r++) {
                    float p = __expf(S[i][j][r] * ascale - mnew[i][r]);
                    psum[i][r] += p;
                    Pw[(i * 16 + kq * 4 + r) * 136 + j * 16 + lm] = (bf16_t)p;
                }
            }
        }
        #pragma unroll
        for (int i = 0; i < 2; i++) {
            #pragma unroll
            for (int r = 0; r < 4; r++) {
                float t = psum[i][r];
                #pragma unroll
                for (int msk = 1; msk <= 8; msk <<= 1) t += __shfl_xor(t, msk);
                lrow[i][r] += t;
            }
        }

        s16x8 ap[2][4];
        #pragma unroll
        for (int i = 0; i < 2; i++)
            #pragma unroll
            for (int kf = 0; kf < 4; kf++)
                ap[i][kf] = *(const s16x8*)(Pw + (i * 16 + lm) * 136 + kf * 32 + kq * 8);
        #pragma unroll
        for (int n = 0; n < 6; n++) {
            s16x8 bv[4];
            #pragma unroll
            for (int kf = 0; kf < 4; kf++)
                bv[kf] = *(const s16x8*)(Vt + (long long)(n * 16 + lm) * SS + kt * 128 + kf * 32 + kq * 8);
            #pragma unroll
            for (int i = 0; i < 2; i++)
                #pragma unroll
                for (int kf = 0; kf < 4; kf++)
                    Oacc[i][n] = __builtin_amdgcn_mfma_f32_16x16x32_bf16(ap[i][kf], bv[kf], Oacc[i][n], 0, 0, 0);
        }
        __syncthreads();
    }

    #pragma unroll
    for (int i = 0; i < 2; i++) {
        #pragma unroll
        for (int n = 0; n < 6; n++) {
            #pragma unroll
            for (int r = 0; r < 4; r++) {
                int row = q0 + i * 16 + kq * 4 + r;
                int col = n * 16 + lm;
                Op[(long long)row * HH + col] = (bf16_t)(Oacc[i][n][r] / lrow[i][r]);
            }
        }
    }
}

// ---------------------------------------------------------------------------
// Vectorized tiled transpose (used for vT only).
// ---------------------------------------------------------------------------
__global__ __launch_bounds__(256)
void transpose_v8(const void* __restrict__ in, bf16_t* __restrict__ out,
                  int R, int C, int ldin, long long inOff,
                  long long sInB, long long sOutB, const int* __restrict__ flagp)
{
    __shared__ bf16_t t[64][72];
    int isbf = flagp ? *flagp : 1;
    int z = blockIdx.z;
    long long base = inOff + (long long)z * sInB;
    bf16_t* op = out + (long long)z * sOutB;
    int cb = blockIdx.x * 64, rb = blockIdx.y * 64;
    int tr = threadIdx.x >> 3;
    int tc = (threadIdx.x & 7) * 8;
    #pragma unroll
    for (int it = 0; it < 2; it++) {
        int r = tr + it * 32;
        int gc = cb + tc;
        if (isbf && gc + 8 <= C) {
            *(s16x8*)&t[r][tc] =
                *(const s16x8*)((const bf16_t*)in + base + (long long)(rb + r) * ldin + gc);
        } else {
            #pragma unroll
            for (int j = 0; j < 8; j++)
                t[r][tc + j] = (gc + j < C)
                    ? (bf16_t)rd_adapt(in, base + (long long)(rb + r) * ldin + gc + j, isbf)
                    : (bf16_t)0.0f;
        }
    }
    __syncthreads();
    int oc = threadIdx.x >> 2;
    int r0 = (threadIdx.x & 3) * 16;
    s16x8 v0, v1;
    #pragma unroll
    for (int j = 0; j < 8; j++) v0[j] = *(short*)&t[r0 + j][oc];
    #pragma unroll
    for (int j = 0; j < 8; j++) v1[j] = *(short*)&t[r0 + 8 + j][oc];
    bf16_t* dst = op + (long long)(cb + oc) * R + rb + r0;
    *(s16x8*)dst = v0;
    *(s16x8*)(dst + 8) = v1;
}

// depthwise conv k=7, 'same' padding along S — vectorized 8-wide channels
__global__ __launch_bounds__(256)
void dconv_kernel(const bf16_t* __restrict__ ebuf, const float* __restrict__ dwT,
                  bf16_t* __restrict__ out)
{
    long long i = (long long)blockIdx.x * 256 + threadIdx.x;   // < B*S*192
    int c8 = (int)(i % 192) * 8;
    long long bs = i / 192;
    int s = (int)(bs % SS);
    float acc[8] = {};
    #pragma unroll
    for (int k = 0; k < 7; k++) {
        int ss = s + k - 3;
        if (ss < 0 || ss >= SS) continue;
        s16x8 v = *(const s16x8*)(ebuf + (bs + (k - 3)) * HH + c8);
        const float4* wp = (const float4*)(dwT + k * HH + c8);
        float4 w0 = wp[0], w1 = wp[1];
        acc[0] += bs2f(v[0]) * w0.x; acc[1] += bs2f(v[1]) * w0.y;
        acc[2] += bs2f(v[2]) * w0.z; acc[3] += bs2f(v[3]) * w0.w;
        acc[4] += bs2f(v[4]) * w1.x; acc[5] += bs2f(v[5]) * w1.y;
        acc[6] += bs2f(v[6]) * w1.z; acc[7] += bs2f(v[7]) * w1.w;
    }
    s16x8 o;
    #pragma unroll
    for (int j = 0; j < 8; j++) o[j] = f2bs(acc[j]);
    *(s16x8*)(out + bs * HH + c8) = o;
}

// conv_out with inline ck-softmax: reads raw ck scores [8192,64] (h*7+k),
// writes right half of ctxcat. Vectorized 8-wide hd.
__global__ __launch_bounds__(256)
void conv_out_kernel(const bf16_t* __restrict__ co, int ldco,
                     const bf16_t* __restrict__ ckb, bf16_t* __restrict__ ctxcat)
{
    long long i = (long long)blockIdx.x * 256 + threadIdx.x;   // < B*S*96
    int ch = (int)(i % 96);
    long long bs = i / 96;
    int s = (int)(bs % SS);
    int hd0 = ch * 8;
    int h = hd0 / HDD;
    // inline softmax over k=7
    const bf16_t* src = ckb + bs * 64 + h * 7;
    float wk[7], mx = -1e30f;
    #pragma unroll
    for (int k = 0; k < 7; k++) { wk[k] = (float)src[k]; mx = fmaxf(mx, wk[k]); }
    float sum = 0.0f;
    #pragma unroll
    for (int k = 0; k < 7; k++) { wk[k] = expf(wk[k] - mx); sum += wk[k]; }
    float inv = 1.0f / sum;
    #pragma unroll
    for (int k = 0; k < 7; k++) wk[k] *= inv;

    float acc[8] = {};
    #pragma unroll
    for (int k = 0; k < 7; k++) {
        int ss = s + k - 3;
        if (ss < 0 || ss >= SS) continue;
        s16x8 v = *(const s16x8*)(co + (bs + (k - 3)) * ldco + hd0);
        #pragma unroll
        for (int j = 0; j < 8; j++) acc[j] += bs2f(v[j]) * wk[k];
    }
    s16x8 o;
    #pragma unroll
    for (int j = 0; j < 8; j++) o[j] = f2bs(acc[j]);
    *(s16x8*)(ctxcat + bs * HH + AHH + hd0) = o;
}

// LayerNorm over 1536 of (y + res) — 192 threads x 8 cols, vectorized
__global__ __launch_bounds__(192)
void ln_kernel(const bf16_t* __restrict__ y, const bf16_t* __restrict__ res,
               const void* __restrict__ g, const void* __restrict__ bta,
               bf16_t* __restrict__ outb, const int* __restrict__ flagp)
{
    int isbf = *flagp;
    long long row = blockIdx.x;
    int tid = threadIdx.x;
    int c0 = tid * 8;
    s16x8 vy = *(const s16x8*)(y + row * HH + c0);
    s16x8 vr = *(const s16x8*)(res + row * HH + c0);
    float x[8], s = 0.0f, s2 = 0.0f;
    #pragma unroll
    for (int j = 0; j < 8; j++) {
        float v = bs2f(vy[j]) + bs2f(vr[j]);
        x[j] = v; s += v; s2 += v * v;
    }
    #pragma unroll
    for (int o = 32; o > 0; o >>= 1) { s += __shfl_down(s, o); s2 += __shfl_down(s2, o); }
    __shared__ float w1[3], w2[3];
    int lane = tid & 63, wv = tid >> 6;
    if (lane == 0) { w1[wv] = s; w2[wv] = s2; }
    __syncthreads();
    float S1 = w1[0] + w1[1] + w1[2];
    float S2 = w2[0] + w2[1] + w2[2];
    float mean = S1 * (1.0f / HH);
    float var  = S2 * (1.0f / HH) - mean * mean;
    float inv  = rsqrtf(var + 1e-12f);
    s16x8 o;
    #pragma unroll
    for (int j = 0; j < 8; j++) {
        float v = (x[j] - mean) * inv * rd_adapt(g, c0 + j, isbf) + rd_adapt(bta, c0 + j, isbf);
        o[j] = f2bs(v);
    }
    *(s16x8*)(outb + row * HH + c0) = o;
}

// maxpool phase 1: per-32-row partial max — 192 threads x 8 cols, vectorized
__global__ __launch_bounds__(192)
void maxpool_p1(const bf16_t* __restrict__ lo, float* __restrict__ part)
{
    int sc = blockIdx.x, b = blockIdx.y;       // 32 chunks x 8 batches
    int tid = threadIdx.x;
    int c0 = tid * 8;
    const bf16_t* p = lo + ((long long)b * SS + sc * 32) * HH + c0;
    float m[8];
    #pragma unroll
    for (int j = 0; j < 8; j++) m[j] = -1e30f;
    for (int r = 0; r < 32; r++) {
        s16x8 v = *(const s16x8*)(p + (long long)r * HH);
        #pragma unroll
        for (int j = 0; j < 8; j++) m[j] = fmaxf(m[j], bs2f(v[j]));
    }
    float* dst = part + ((long long)b * 32 + sc) * HH + c0;
    *(float4*)(dst)     = make_float4(m[0], m[1], m[2], m[3]);
    *(float4*)(dst + 4) = make_float4(m[4], m[5], m[6], m[7]);
}

// fused maxpool phase 2 + decoder — 192 threads x 8 cols
__global__ __launch_bounds__(192)
void pool_decode(const float* __restrict__ part, const void* __restrict__ wd,
                 const void* __restrict__ bd, void* __restrict__ out,
                 const int* __restrict__ flagp)
{
    int isbf = *flagp;
    int b = blockIdx.x;
    int tid = threadIdx.x;
    int c0 = tid * 8;
    float m[8];
    #pragma unroll
    for (int j = 0; j < 8; j++) m[j] = -1e30f;
    for (int ch = 0; ch < 32; ch++) {
        const float4* q = (const float4*)(part + ((long long)b * 32 + ch) * HH + c0);
        float4 a = q[0], c = q[1];
        m[0] = fmaxf(m[0], a.x); m[1] = fmaxf(m[1], a.y);
        m[2] = fmaxf(m[2], a.z); m[3] = fmaxf(m[3], a.w);
        m[4] = fmaxf(m[4], c.x); m[5] = fmaxf(m[5], c.y);
        m[6] = fmaxf(m[6], c.z); m[7] = fmaxf(m[7], c.w);
    }
    float s = 0.0f;
    #pragma unroll
    for (int j = 0; j < 8; j++) s += m[j] * rd_adapt(wd, c0 + j, isbf);
    #pragma unroll
    for (int o = 32; o > 0; o >>= 1) s += __shfl_down(s, o);
    __shared__ float sa[3];
    int lane = tid & 63, wv = tid >> 6;
    if (lane == 0) sa[wv] = s;
    __syncthreads();
    if (tid == 0) {
        float r = sa[0] + sa[1] + sa[2] + rd_adapt(bd, 0, isbf);
        if (isbf) ((bf16_t*)out)[b] = (bf16_t)r;
        else      ((float*)out)[b]  = r;
    }
}

// ---------------------------------------------------------------------------
extern "C" void kernel_launch(void* const* d_in, const int* in_sizes, int n_in,
                              void* d_out, int out_size, void* d_ws, size_t ws_size,
                              hipStream_t stream)
{
    const void* embed = d_in[0];
    const void* wq  = d_in[1];  const void* bq  = d_in[2];
    const void* wk  = d_in[3];  const void* bk  = d_in[4];
    const void* wv  = d_in[5];  const void* bv  = d_in[6];
    const void* dw  = d_in[7];  const void* pw  = d_in[8];  const void* sep_b = d_in[9];
    const void* wck = d_in[10]; const void* bck = d_in[11];
    const void* wco = d_in[12]; const void* bco = d_in[13];
    const void* wso = d_in[14]; const void* bso = d_in[15];
    const void* ln1g = d_in[16]; const void* ln1b = d_in[17];
    const void* wi  = d_in[18]; const void* bi  = d_in[19];
    const void* wo  = d_in[20]; const void* bo  = d_in[21];
    const void* ln2g = d_in[22]; const void* ln2b = d_in[23];
    const void* wd  = d_in[24]; const void* bd  = d_in[25];
    (void)ws_size; (void)in_sizes; (void)n_in; (void)out_size;

    // ---- arena (143.2 MB), lifetime-aliased ----
    char* ws = (char*)d_ws;
    char* A  = ws;                          // 50.33 MB: qkvco -> ybuf/interb/lout
    char* B  = ws + 50331648;               // 25.17 MB: wT_all -> dconvb -> ckb -> vT -> wiT+woT
    char* C_ = ws + 75497472;               // 12.58 MB: sepb -> mpart
    char* D  = ws + 88080384;               // 25.17 MB: ctxcat -> attn
    char* E  = ws + 113246208;              // 25.17 MB: ebuf -> y2
    char* F  = ws + 138412032;              //  4.72 MB: pwT+wckT -> wsoT
    char* XP = ws + 143130624;              //  flag + cbias + dwT

    bf16_t* qkvco  = (bf16_t*)A;                    // [8192,3072]
    bf16_t* ybuf   = (bf16_t*)A;                    // [8192,1536] (after flash)
    bf16_t* interb = (bf16_t*)A;                    // [8192,3072] (after ln1)
    bf16_t* lout   = (bf16_t*)A;                    // [8192,1536] (after wo)
    bf16_t* wT_all = (bf16_t*)B;                    // [3072,1536] (merged gemm)
    bf16_t* dconvb = (bf16_t*)B;                    // [8192,1536] (after merged)
    bf16_t* ckb    = (bf16_t*)B;                    // [8192,64]   (after sep)
    bf16_t* vT     = (bf16_t*)B;                    // [8,768,1024] (after conv_out)
    bf16_t* wiT    = (bf16_t*)B;                    // [3072,1536] (after flash)
    bf16_t* woT    = (bf16_t*)(B + 9437184);        // [1536,3072] (after flash)
    bf16_t* sepb   = (bf16_t*)C_;                   // [8192,768]
    float*  mpart  = (float*)C_;                    // [8,32,1536] f32
    bf16_t* ctxcat = (bf16_t*)D;                    // [8192,1536]
    bf16_t* attn   = (bf16_t*)D;                    // [8192,1536]
    bf16_t* ebuf   = (bf16_t*)E;                    // [8192,1536]
    bf16_t* y2     = (bf16_t*)E;                    // [8192,1536]
    bf16_t* pwT    = (bf16_t*)F;                    // [768,1536]
    bf16_t* wckT   = (bf16_t*)(F + 2359296);        // [128,768]
    bf16_t* wsoT   = (bf16_t*)F;                    // [1536,1536] (after ck gemm)
    int*    flag   = (int*)XP;
    bf16_t* cbias  = (bf16_t*)(XP + 256);           // [3072]
    float*  dwT    = (float*)(XP + 8192);           // [7,1536] f32

    dim3 blk(256);

    // big GEMMs (N=3072 shapes): 256x256 pipelined
    auto gemm_big = [&](const bf16_t* Ai, const bf16_t* Bt, bf16_t* Ci, const void* bias,
                        const bf16_t* emul, int lde, const int* fl,
                        int M, int N, int Kd, int lda, int ldb, int ldc, int act) {
        int tn = N / 256;
        dim3 g((M / 256) * tn);
        gemm256<<<g, dim3(512), 0, stream>>>(Ai, Bt, Ci, bias, emul, lde, fl,
                                             M, N, Kd, lda, ldb, ldc, act, tn);
    };
    // 128x128 path (sep, ck, wso, wo — full-occupancy grids)
    auto gemm = [&](const bf16_t* Ai, const bf16_t* Bt, bf16_t* Ci, const void* bias,
                    long long biasOff, const bf16_t* emul, int lde, const int* fl,
                    int M, int N, int Kd, int lda, int ldb, int ldc,
                    float scale, int act, int beta, int nlim) {
        dim3 g(M / 128, (N + 127) / 128, 1);
        gemm_tile<<<g, blk, 0, stream>>>(Ai, Bt, Ci, bias, biasOff, emul, lde, fl,
                                         M, N, Kd, lda, ldb, ldc,
                                         scale, act, beta, nlim);
    };

    // --- dtype probe, weight prep (one launch), embed conversion ---
    detect_kernel<<<dim3(1), blk, 0, stream>>>(embed, flag);
    prep_weights<<<dim3(1518), blk, 0, stream>>>(wq, wk, wv, wco, pw, wck, dw,
                                                 bq, bk, bv, bco,
                                                 wT_all, pwT, wckT, dwT, cbias, flag);
    convert_embed<<<dim3(6144), blk, 0, stream>>>(embed, ebuf, flag);

    // --- merged Q|K|V|co projection ---
    gemm_big(ebuf, wT_all, qkvco, cbias, nullptr, 0, nullptr,
             8192, 3072, 1536, HH, HH, 3072, 0);

    // --- separable conv: depthwise (vectorized), pointwise fused with *q ---
    dconv_kernel<<<dim3((BB * SS * 192) / 256), blk, 0, stream>>>(ebuf, dwT, dconvb);
    gemm(dconvb, pwT, sepb, sep_b, 0, qkvco, 3072, flag,
         8192, 768, 1536, HH, HH, AHH, 1.0f, 0, 0, 767);

    // --- span conv kernels (ck scores -> softmax inline in conv_out) ---
    gemm(sepb, wckT, ckb, bck, 0, nullptr, 0, flag,
         8192, 56, 768, AHH, AHH, 64, 1.0f, 0, 0, 127);
    conv_out_kernel<<<dim3((BB * SS * 96) / 256), blk, 0, stream>>>(qkvco + 2304, 3072, ckb, ctxcat);

    // --- fused flash attention (XCD-local grid: bh fastest) ---
    transpose_v8<<<dim3(12, 16, 8), blk, 0, stream>>>(qkvco, vT, 1024, 768, 3072, 1536,
                                                      1024ll * 3072, 768ll * 1024, nullptr);
    flash_attn<<<dim3(64, 8), blk, 0, stream>>>(qkvco, vT, ctxcat);

    // --- late weight prep (one launch; B slot free after flash) ---
    prep_late<<<dim3(2880), blk, 0, stream>>>(wso, wi, wo, wsoT, wiT, woT, flag);

    // --- self output (128^2 path, 768 WGs) + LN1 ---
    gemm(ctxcat, wsoT, ybuf, bso, 0, nullptr, 0, flag,
         8192, 1536, 1536, HH, HH, HH, 1.0f, 0, 0, 1535);
    ln_kernel<<<dim3(8192), dim3(192), 0, stream>>>(ybuf, ebuf, ln1g, ln1b, attn, flag);

    // --- FFN: wi (gemm256, 384 WGs) -> wo (128^2 path, 768 WGs) + LN2 ---
    gemm_big(attn, wiT, interb, bi, nullptr, 0, flag,
             8192, 3072, 1536, HH, HH, IMM, 1);
    gemm(interb, woT, y2, bo, 0, nullptr, 0, flag,
         8192, 1536, 3072, IMM, IMM, HH, 1.0f, 0, 0, 1535);
    ln_kernel<<<dim3(8192), dim3(192), 0, stream>>>(y2, attn, ln2g, ln2b, lout, flag);

    // --- pool + decode (partials in dead sepb slot) ---
    maxpool_p1<<<dim3(32, 8), dim3(192), 0, stream>>>(lout, mpart);
    pool_decode<<<dim3(BB), dim3(192), 0, stream>>>(mpart, wd, bd, d_out, flag);
}